// Round 5
// baseline (279.819 us; speedup 1.0000x reference)
//
#include <hip/hip_runtime.h>
#include <hip/hip_bf16.h>

// DecorrelatedBatchNorm1d (ZCA whitening), B=65536, F=512, fp32 in/out.
// Big-ws pipeline:
//   K1 k_conv:     xb = bf16(x) row-major + colsum   (pure stream, LDS-reduced)
//   K2 k_tr:       xbT = transpose(xb)               (reg-only 8x8 v_perm transpose)
//   K3 k_cov:      S = xbT * xbT^T upper-triangle    (bf16 MFMA, split-K=32, atomics)
//   K4 k_finalize: mean, E = S/(B-1) corrected - I + eps
//   K5 k_poly s0:  E2 = E@E; G = c3*E + c4*E2        (deg-4 Taylor of (I+E)^-1/2)
//   K6 k_poly s1:  W = I + c1*E + c2*E2 + E2@G -> Wb; tacc = mean^T W
//   K7 k_out_b:    out = (xb@W - tacc)*weight + bias (pure bf16 MFMA GEMM)
// Small-ws fallback: old k_prep (fp32-LDS transpose) + k_out_f (fp32 reg-staged A).

#define F 512
#define LDT 65536

typedef unsigned short u16;
using bf16x8 = __attribute__((ext_vector_type(8))) short;
using f32x4  = __attribute__((ext_vector_type(4))) float;

// ---- workspace layout (bytes) ----
#define WS_S      0u
#define WS_COLSUM 1048576u
#define WS_TACC   1050624u
#define WS_MEAN   1052672u
#define WS_E      1054720u
#define WS_E2     (WS_E   + 1048576u)
#define WS_EB     (WS_E2  + 1048576u)
#define WS_E2B    (WS_EB  + 524288u)
#define WS_GB     (WS_E2B + 524288u)
#define WS_WB     (WS_GB  + 524288u)
#define WS_XB     (WS_WB  + 524288u)
#define WS_NEED_BIG (WS_XB + 67108864u)

__device__ __forceinline__ u16 f2bf(float x) {
  union { float f; unsigned u; } v; v.f = x;
  return (u16)((v.u + 0x7fffu + ((v.u >> 16) & 1u)) >> 16);
}

// zip of two dwords at u16 granularity: zlo = [A.lo16, B.lo16], zhi = [A.hi16, B.hi16]
__device__ __forceinline__ unsigned zlo(unsigned A, unsigned B) {
  return __builtin_amdgcn_perm(B, A, 0x05040100u);
}
__device__ __forceinline__ unsigned zhi(unsigned A, unsigned B) {
  return __builtin_amdgcn_perm(B, A, 0x07060302u);
}

__device__ __forceinline__ void async_cp16(const void* g, void* l) {
  __builtin_amdgcn_global_load_lds(
      (const __attribute__((address_space(1))) unsigned int*)g,
      (__attribute__((address_space(3))) unsigned int*)l, 16, 0, 0);
}

// ---- [128 rows][64 k] bf16 tile staging ----
// LDS dest linear; source pre-swizzled: LDS row r chunk c holds global chunk c^(r&7).
__device__ __forceinline__ void stage_tile(u16* dst, const u16* src, size_t stride, int t) {
#pragma unroll
  for (int q = 0; q < 4; ++q) {
    int idx = q * 256 + t;
    int c = idx >> 3, ko = idx & 7;
    async_cp16(src + (size_t)c * stride + (size_t)((ko ^ (c & 7)) << 3), dst + idx * 8);
  }
}

__device__ __forceinline__ void stage512(u16* dst, const u16* src, size_t stride, int t) {
#pragma unroll
  for (int q = 0; q < 2; ++q) {
    int idx = q * 512 + t;
    int c = idx >> 3, ko = idx & 7;
    async_cp16(src + (size_t)c * stride + (size_t)((ko ^ (c & 7)) << 3), dst + idx * 8);
  }
}

__device__ __forceinline__ void stage64(u16* dst, const u16* src, size_t stride, int t) {
#pragma unroll
  for (int q = 0; q < 2; ++q) {
    int idx = q * 256 + t;
    int r = idx >> 3, ko = idx & 7;
    async_cp16(src + (size_t)r * stride + (size_t)((ko ^ (r & 7)) << 3), dst + idx * 8);
  }
}

// 128x128 tile step, 4 waves (k_cov)
__device__ __forceinline__ void mm_step(const u16* As, const u16* Bs, int wr, int wc,
                                        int l, f32x4 acc[4][4]) {
#pragma unroll
  for (int kh = 0; kh < 2; ++kh) {
    bf16x8 a[4], b[4];
#pragma unroll
    for (int m = 0; m < 4; ++m) {
      int row = wr * 64 + m * 16 + (l & 15);
      int ch = (kh * 4 + (l >> 4)) ^ (row & 7);
      a[m] = *(const bf16x8*)(As + row * 64 + ch * 8);
    }
#pragma unroll
    for (int n = 0; n < 4; ++n) {
      int row = wc * 64 + n * 16 + (l & 15);
      int ch = (kh * 4 + (l >> 4)) ^ (row & 7);
      b[n] = *(const bf16x8*)(Bs + row * 64 + ch * 8);
    }
#pragma unroll
    for (int m = 0; m < 4; ++m)
#pragma unroll
      for (int n = 0; n < 4; ++n)
        acc[m][n] = __builtin_amdgcn_mfma_f32_16x16x32_bf16(a[m], b[n], acc[m][n], 0, 0, 0);
  }
}

// 128x128 tile step, 8 waves (k_out): wave-tile 64x32
__device__ __forceinline__ void mm_step8(const u16* As, const u16* Bs, int wr, int wc,
                                         int l, f32x4 acc[4][2]) {
#pragma unroll
  for (int kh = 0; kh < 2; ++kh) {
    bf16x8 a[4], b[2];
#pragma unroll
    for (int m = 0; m < 4; ++m) {
      int row = wr * 64 + m * 16 + (l & 15);
      int ch = (kh * 4 + (l >> 4)) ^ (row & 7);
      a[m] = *(const bf16x8*)(As + row * 64 + ch * 8);
    }
#pragma unroll
    for (int n = 0; n < 2; ++n) {
      int row = wc * 32 + n * 16 + (l & 15);
      int ch = (kh * 4 + (l >> 4)) ^ (row & 7);
      b[n] = *(const bf16x8*)(Bs + row * 64 + ch * 8);
    }
#pragma unroll
    for (int m = 0; m < 4; ++m)
#pragma unroll
      for (int n = 0; n < 2; ++n)
        acc[m][n] = __builtin_amdgcn_mfma_f32_16x16x32_bf16(a[m], b[n], acc[m][n], 0, 0, 0);
  }
}

// 64x64 tile step, 4 waves (poly)
__device__ __forceinline__ void mm64(const u16* As, const u16* Bs, int wr, int wc,
                                     int l, f32x4 acc[2][2]) {
#pragma unroll
  for (int kh = 0; kh < 2; ++kh) {
    bf16x8 a[2], b[2];
#pragma unroll
    for (int m = 0; m < 2; ++m) {
      int row = wr * 32 + m * 16 + (l & 15);
      int ch = (kh * 4 + (l >> 4)) ^ (row & 7);
      a[m] = *(const bf16x8*)(As + row * 64 + ch * 8);
    }
#pragma unroll
    for (int n = 0; n < 2; ++n) {
      int row = wc * 32 + n * 16 + (l & 15);
      int ch = (kh * 4 + (l >> 4)) ^ (row & 7);
      b[n] = *(const bf16x8*)(Bs + row * 64 + ch * 8);
    }
#pragma unroll
    for (int m = 0; m < 2; ++m)
#pragma unroll
      for (int n = 0; n < 2; ++n)
        acc[m][n] = __builtin_amdgcn_mfma_f32_16x16x32_bf16(a[m], b[n], acc[m][n], 0, 0, 0);
  }
}

// ---------------- K1: xb = bf16(x) + colsum (pure stream) ----------------
// 1024 blocks x 256 thr; block = 64 rows x 512 feats; thread owns feat-group
// cg = t&127 (4 feats) across 64 rows.
__global__ __launch_bounds__(256) void k_conv(const float* __restrict__ x,
                                              u16* __restrict__ xb,
                                              float* __restrict__ colsum) {
  __shared__ float red[1024];
  const int t = threadIdx.x;
  const size_t rbase = (size_t)blockIdx.x * 64;
  const int cg = t & 127, r0 = t >> 7;
  float s0 = 0, s1 = 0, s2 = 0, s3 = 0;
#pragma unroll
  for (int q = 0; q < 32; ++q) {
    size_t r = rbase + r0 + q * 2;
    float4 v = *(const float4*)(x + r * F + cg * 4);
    s0 += v.x; s1 += v.y; s2 += v.z; s3 += v.w;
    ushort4 o;
    o.x = f2bf(v.x); o.y = f2bf(v.y); o.z = f2bf(v.z); o.w = f2bf(v.w);
    *(ushort4*)(xb + r * F + cg * 4) = o;
  }
  float4 sv; sv.x = s0; sv.y = s1; sv.z = s2; sv.w = s3;
  *(float4*)(red + r0 * 512 + cg * 4) = sv;
  __syncthreads();
  if (t < 128) {
    float4 a = *(const float4*)(red + t * 4);
    float4 b = *(const float4*)(red + 512 + t * 4);
    atomicAdd(colsum + t * 4 + 0, a.x + b.x);
    atomicAdd(colsum + t * 4 + 1, a.y + b.y);
    atomicAdd(colsum + t * 4 + 2, a.z + b.z);
    atomicAdd(colsum + t * 4 + 3, a.w + b.w);
  }
}

// ---------------- K2: xbT = transpose(xb), register-only 8x8 blocks ----------------
// grid (1024, 2), 256 thr. Thread (tx=t&7 batch-block, ty=t>>3 feat-block) owns an
// 8x8 bf16 block: 8x 16B loads, 32 v_perm, 8x 16B stores (128B/feat segments).
__global__ __launch_bounds__(256) void k_tr(const u16* __restrict__ xb,
                                            u16* __restrict__ xbT) {
  const int t = threadIdx.x;
  const int tx = t & 7, ty = t >> 3;
  const size_t rb = (size_t)blockIdx.x * 64 + tx * 8;
  const int cb = blockIdx.y * 256 + ty * 8;
  uint4 v[8];
#pragma unroll
  for (int i = 0; i < 8; ++i)
    v[i] = *(const uint4*)(xb + (rb + i) * F + cb);
#pragma unroll
  for (int c = 0; c < 8; ++c) {
    const int k = c >> 1;
    uint4 o;
    if ((c & 1) == 0) {
      o.x = zlo(((const unsigned*)&v[0])[k], ((const unsigned*)&v[1])[k]);
      o.y = zlo(((const unsigned*)&v[2])[k], ((const unsigned*)&v[3])[k]);
      o.z = zlo(((const unsigned*)&v[4])[k], ((const unsigned*)&v[5])[k]);
      o.w = zlo(((const unsigned*)&v[6])[k], ((const unsigned*)&v[7])[k]);
    } else {
      o.x = zhi(((const unsigned*)&v[0])[k], ((const unsigned*)&v[1])[k]);
      o.y = zhi(((const unsigned*)&v[2])[k], ((const unsigned*)&v[3])[k]);
      o.z = zhi(((const unsigned*)&v[4])[k], ((const unsigned*)&v[5])[k]);
      o.w = zhi(((const unsigned*)&v[6])[k], ((const unsigned*)&v[7])[k]);
    }
    *(uint4*)(xbT + (size_t)(cb + c) * LDT + rb) = o;
  }
}

// ---------------- K3: S = X^T X, upper-triangle 128-tiles, split-K=32 ----------------
__global__ __launch_bounds__(256) void k_cov(const u16* __restrict__ xbT,
                                             float* __restrict__ S) {
  __shared__ __attribute__((aligned(16))) u16 As[2][128 * 64];
  __shared__ __attribute__((aligned(16))) u16 Bs[2][128 * 64];
  const int b = blockIdx.x;
  const int i = b >> 3;               // 0..39
  const int slab = (b & 7) * 4 + i / 10;
  const int tid = i % 10;
  int ta, tb;
  if (tid < 4)      { ta = 0; tb = tid; }
  else if (tid < 7) { ta = 1; tb = tid - 3; }
  else if (tid < 9) { ta = 2; tb = tid - 5; }
  else              { ta = 3; tb = 3; }
  const int a0 = ta * 128, b0 = tb * 128;
  const size_t kbase = (size_t)slab * 2048;
  const int t = threadIdx.x;
  const int l = t & 63, w = t >> 6, wr = w >> 1, wc = w & 1;
  f32x4 acc[4][4] = {};
  const u16* Abase = xbT + (size_t)a0 * LDT + kbase;
  const u16* Bbase = xbT + (size_t)b0 * LDT + kbase;
  stage_tile(As[0], Abase, LDT, t);
  stage_tile(Bs[0], Bbase, LDT, t);
  __syncthreads();
  for (int it = 0; it < 32; ++it) {
    int cur = it & 1;
    if (it < 31) {
      stage_tile(As[cur ^ 1], Abase + (it + 1) * 64, LDT, t);
      stage_tile(Bs[cur ^ 1], Bbase + (it + 1) * 64, LDT, t);
    }
    mm_step(As[cur], Bs[cur], wr, wc, l, acc);
    __syncthreads();
  }
#pragma unroll
  for (int m = 0; m < 4; ++m) {
    int rg = a0 + wr * 64 + m * 16 + ((l >> 4) << 2);
#pragma unroll
    for (int n = 0; n < 4; ++n) {
      int cg = b0 + wc * 64 + n * 16 + (l & 15);
#pragma unroll
      for (int r = 0; r < 4; ++r)
        atomicAdd(S + (size_t)(rg + r) * F + cg, acc[m][n][r]);
    }
  }
}

// ---------------- K4: finalize mean + E = cov - I ----------------
__global__ __launch_bounds__(256) void k_finalize(const float* __restrict__ S,
                                                  const float* __restrict__ colsum,
                                                  float* __restrict__ mean,
                                                  float* __restrict__ E,
                                                  u16* __restrict__ Eb) {
  int gid = blockIdx.x * 256 + threadIdx.x;
  int i = gid >> 9, j = gid & 511;
  float mi = colsum[i] * (1.0f / 65536.0f);
  float mj = colsum[j] * (1.0f / 65536.0f);
  float sv = ((i >> 7) <= (j >> 7)) ? S[(size_t)i * F + j] : S[(size_t)j * F + i];
  float cov = (sv - 65536.0f * mi * mj) * (1.0f / 65535.0f);
  float e = cov + ((i == j) ? (0.001f - 1.0f) : 0.0f);
  E[gid] = e;
  Eb[gid] = f2bf(e);
  if (gid < F) mean[gid] = colsum[gid] * (1.0f / 65536.0f);
}

// ---------------- K5/K6: degree-4 Taylor of (I+E)^(-1/2) ----------------
__global__ __launch_bounds__(256) void k_poly(char* __restrict__ wsb, int stg) {
  __shared__ __attribute__((aligned(16))) u16 As[2][64 * 64];
  __shared__ __attribute__((aligned(16))) u16 Bs[2][64 * 64];
  const int tile = blockIdx.x;
  const int tr = tile >> 3, tc = tile & 7;
  const int r0 = tr * 64, c0 = tc * 64;
  const u16* Eb  = (const u16*)(wsb + WS_EB);
  const u16* E2b = (const u16*)(wsb + WS_E2B);
  const u16* Gb  = (const u16*)(wsb + WS_GB);
  const u16* Ab; const u16* Bb;
  if (stg == 0) { Ab = Eb;  Bb = Eb; }
  else          { Ab = E2b; Bb = Gb; }
  const int t = threadIdx.x;
  const int l = t & 63, w = t >> 6, wr = w >> 1, wc = w & 1;
  f32x4 acc[2][2] = {};
  stage64(As[0], Ab + (size_t)r0 * F, F, t);
  stage64(Bs[0], Bb + (size_t)c0 * F, F, t);
  __syncthreads();
  for (int it = 0; it < 8; ++it) {
    int cur = it & 1;
    if (it < 7) {
      stage64(As[cur ^ 1], Ab + (size_t)r0 * F + (it + 1) * 64, F, t);
      stage64(Bs[cur ^ 1], Bb + (size_t)c0 * F + (it + 1) * 64, F, t);
    }
    mm64(As[cur], Bs[cur], wr, wc, l, acc);
    __syncthreads();
  }
  const float* Ef  = (const float*)(wsb + WS_E);
  const float* E2f = (const float*)(wsb + WS_E2);
  const float* mean = (const float*)(wsb + WS_MEAN);
  float* tacc = (float*)(wsb + WS_TACC);
  const float c1 = -0.5f, c2 = 0.375f, c3 = -0.3125f, c4 = 35.0f / 128.0f;
#pragma unroll
  for (int n = 0; n < 2; ++n) {
    int cg = c0 + wc * 32 + n * 16 + (l & 15);
    float ts = 0.0f;
#pragma unroll
    for (int m = 0; m < 2; ++m) {
#pragma unroll
      for (int r = 0; r < 4; ++r) {
        int rg = r0 + wr * 32 + m * 16 + ((l >> 4) << 2) + r;
        size_t o = (size_t)rg * F + cg;
        float v = acc[m][n][r];
        if (stg == 0) {
          ((float*)(wsb + WS_E2))[o] = v;
          ((u16*)(wsb + WS_E2B))[o] = f2bf(v);
          ((u16*)(wsb + WS_GB))[o]  = f2bf(c3 * Ef[o] + c4 * v);
        } else {
          float wv = c1 * Ef[o] + c2 * E2f[o] + v + ((rg == cg) ? 1.0f : 0.0f);
          ((u16*)(wsb + WS_WB))[o] = f2bf(wv);
          ts += mean[rg] * wv;
        }
      }
    }
    if (stg == 1) atomicAdd(tacc + cg, ts);
  }
}

// ---------------- K7: out = (xb@W - tacc)*w + b  (pure bf16 GEMM) --------
__global__ __launch_bounds__(512) void k_out_b(const u16* __restrict__ xb,
                                               const u16* __restrict__ Wb,
                                               const float* __restrict__ tacc,
                                               const float* __restrict__ wgt,
                                               const float* __restrict__ bias,
                                               float* __restrict__ out) {
  __shared__ __attribute__((aligned(16))) u16 As[2][128 * 64];
  __shared__ __attribute__((aligned(16))) u16 Bs[2][128 * 64];
  const int b = blockIdx.x;
  const int i = b >> 3;
  const int rt = (b & 7) * 64 + (i >> 2), ct = i & 3;
  const int i0 = rt * 128, j0 = ct * 128;
  const int t = threadIdx.x;
  const int l = t & 63, w = t >> 6, wr = w >> 2, wc = w & 3;
  f32x4 acc[4][2] = {};
  const u16* Abase = xb + (size_t)i0 * F;
  const u16* Bbase = Wb + (size_t)j0 * F;
  stage512(As[0], Abase, F, t);
  stage512(Bs[0], Bbase, F, t);
  __syncthreads();
  for (int it = 0; it < 8; ++it) {
    int cur = it & 1;
    if (it < 7) {
      stage512(As[cur ^ 1], Abase + (it + 1) * 64, F, t);
      stage512(Bs[cur ^ 1], Bbase + (it + 1) * 64, F, t);
    }
    mm_step8(As[cur], Bs[cur], wr, wc, l, acc);
    __syncthreads();
  }
#pragma unroll
  for (int n = 0; n < 2; ++n) {
    int cg = j0 + wc * 32 + n * 16 + (l & 15);
    float mv = tacc[cg];
    float wv = wgt[cg], bv = bias[cg];
#pragma unroll
    for (int m = 0; m < 4; ++m) {
      int rb = i0 + wr * 64 + m * 16 + ((l >> 4) << 2);
#pragma unroll
      for (int r = 0; r < 4; ++r) {
        size_t o = (size_t)(rb + r) * F + cg;
        out[o] = (acc[m][n][r] - mv) * wv + bv;
      }
    }
  }
}

// ---------------- small-ws fallback: fp32-LDS transpose prep ----------------
__global__ __launch_bounds__(256) void k_prep(const float* __restrict__ x,
                                              u16* __restrict__ xbT,
                                              float* __restrict__ colsum) {
  __shared__ __attribute__((aligned(16))) float tile[128 * 65];
  const int t = threadIdx.x;
  const int rt = blockIdx.x, ct = blockIdx.y;
  const int r0 = rt * 128, c0 = ct * 64;
  const int c4 = t & 15, rg = t >> 4;
  float cs0 = 0, cs1 = 0, cs2 = 0, cs3 = 0;
#pragma unroll
  for (int p = 0; p < 8; ++p) {
    int r = rg + p * 16;
    float4 v = *(const float4*)(x + (size_t)(r0 + r) * F + c0 + c4 * 4);
    cs0 += v.x; cs1 += v.y; cs2 += v.z; cs3 += v.w;
    float* tp = tile + r * 65 + c4 * 4;
    tp[0] = v.x; tp[1] = v.y; tp[2] = v.z; tp[3] = v.w;
  }
  __syncthreads();
  const int l = t & 63, w = t >> 6;
  const int a = l & 15, bg = l >> 4;
#pragma unroll
  for (int cp = 0; cp < 4; ++cp) {
    int c = cp * 16 + w * 4 + bg;
#pragma unroll
    for (int h = 0; h < 2; ++h) {
      int rb = 4 * a + 64 * h;
      ushort4 o;
      o.x = f2bf(tile[(rb + 0) * 65 + c]);
      o.y = f2bf(tile[(rb + 1) * 65 + c]);
      o.z = f2bf(tile[(rb + 2) * 65 + c]);
      o.w = f2bf(tile[(rb + 3) * 65 + c]);
      *(ushort4*)(xbT + (size_t)(c0 + c) * LDT + r0 + rb) = o;
    }
  }
  __syncthreads();
  tile[rg * 64 + c4 * 4 + 0] = cs0;
  tile[rg * 64 + c4 * 4 + 1] = cs1;
  tile[rg * 64 + c4 * 4 + 2] = cs2;
  tile[rg * 64 + c4 * 4 + 3] = cs3;
  __syncthreads();
  if (t < 64) {
    float s = 0;
#pragma unroll
    for (int g = 0; g < 16; ++g) s += tile[g * 64 + t];
    atomicAdd(colsum + c0 + t, s);
  }
}

// ---------------- small-ws fallback: fp32 reg-staged A ----------------
__global__ __launch_bounds__(512) void k_out_f(const float* __restrict__ x,
                                               const u16* __restrict__ Wb,
                                               const float* __restrict__ tacc,
                                               const float* __restrict__ wgt,
                                               const float* __restrict__ bias,
                                               float* __restrict__ out) {
  __shared__ __attribute__((aligned(16))) u16 As[2][128 * 64];
  __shared__ __attribute__((aligned(16))) u16 Bs[2][128 * 64];
  const int b = blockIdx.x;
  const int i = b >> 3;
  const int rt = (b & 7) * 64 + (i >> 2), ct = i & 3;
  const int i0 = rt * 128, j0 = ct * 128;
  const int t = threadIdx.x;
  const int l = t & 63, w = t >> 6, wr = w >> 2, wc = w & 3;
  f32x4 acc[4][2] = {};
  float4 ld[4];
  stage512(Bs[0], Wb + (size_t)j0 * F, F, t);
#pragma unroll
  for (int q = 0; q < 4; ++q) {
    int idx = q * 512 + t, r = idx >> 4, kc = idx & 15;
    ld[q] = *(const float4*)(x + (size_t)(i0 + r) * F + kc * 4);
  }
#pragma unroll
  for (int q = 0; q < 4; ++q) {
    int idx = q * 512 + t, r = idx >> 4, kc = idx & 15;
    ushort4 o;
    o.x = f2bf(ld[q].x); o.y = f2bf(ld[q].y); o.z = f2bf(ld[q].z); o.w = f2bf(ld[q].w);
    *(ushort4*)(As[0] + r * 64 + (((kc >> 1) ^ (r & 7)) << 3) + ((kc & 1) << 2)) = o;
  }
  __syncthreads();
  for (int it = 0; it < 8; ++it) {
    int cur = it & 1;
    if (it < 7) {
      int kk = (it + 1) * 64;
#pragma unroll
      for (int q = 0; q < 4; ++q) {
        int idx = q * 512 + t, r = idx >> 4, kc = idx & 15;
        ld[q] = *(const float4*)(x + (size_t)(i0 + r) * F + kk + kc * 4);
      }
      stage512(Bs[cur ^ 1], Wb + (size_t)j0 * F + kk, F, t);
    }
    mm_step8(As[cur], Bs[cur], wr, wc, l, acc);
    if (it < 7) {
#pragma unroll
      for (int q = 0; q < 4; ++q) {
        int idx = q * 512 + t, r = idx >> 4, kc = idx & 15;
        ushort4 o;
        o.x = f2bf(ld[q].x); o.y = f2bf(ld[q].y); o.z = f2bf(ld[q].z); o.w = f2bf(ld[q].w);
        *(ushort4*)(As[cur ^ 1] + r * 64 + (((kc >> 1) ^ (r & 7)) << 3) + ((kc & 1) << 2)) = o;
      }
    }
    __syncthreads();
  }
#pragma unroll
  for (int n = 0; n < 2; ++n) {
    int cg = j0 + wc * 32 + n * 16 + (l & 15);
    float mv = tacc[cg];
    float wv = wgt[cg], bv = bias[cg];
#pragma unroll
    for (int m = 0; m < 4; ++m) {
      int rb = i0 + wr * 64 + m * 16 + ((l >> 4) << 2);
#pragma unroll
      for (int r = 0; r < 4; ++r) {
        size_t o = (size_t)(rb + r) * F + cg;
        out[o] = (acc[m][n][r] - mv) * wv + bv;
      }
    }
  }
}

extern "C" void kernel_launch(void* const* d_in, const int* in_sizes, int n_in,
                              void* d_out, int out_size, void* d_ws, size_t ws_size,
                              hipStream_t stream) {
  (void)in_sizes; (void)n_in; (void)out_size;
  const float* x      = (const float*)d_in[0];
  const float* weight = (const float*)d_in[1];
  const float* bias   = (const float*)d_in[2];
  float* out = (float*)d_out;
  char* ws   = (char*)d_ws;
  // xbT (64 MiB) overlays d_out; dead before k_out overwrites d_out.
  u16* xbT = (u16*)d_out;
  const bool big = ws_size >= (size_t)WS_NEED_BIG;
  u16* xb = (u16*)(ws + WS_XB);

  float* S      = (float*)(ws + WS_S);
  float* colsum = (float*)(ws + WS_COLSUM);
  float* tacc   = (float*)(ws + WS_TACC);
  float* mean   = (float*)(ws + WS_MEAN);

  hipMemsetAsync(ws, 0, WS_MEAN, stream);  // zero S + colsum + tacc

  if (big) {
    k_conv<<<dim3(1024), dim3(256), 0, stream>>>(x, xb, colsum);
    k_tr<<<dim3(1024, 2), dim3(256), 0, stream>>>(xb, xbT);
  } else {
    k_prep<<<dim3(512, 8), dim3(256), 0, stream>>>(x, xbT, colsum);
  }
  k_cov<<<dim3(320), dim3(256), 0, stream>>>(xbT, S);
  k_finalize<<<dim3(1024), dim3(256), 0, stream>>>(S, colsum, mean,
                                                   (float*)(ws + WS_E),
                                                   (u16*)(ws + WS_EB));
  k_poly<<<dim3(64), dim3(256), 0, stream>>>(ws, 0);
  k_poly<<<dim3(64), dim3(256), 0, stream>>>(ws, 1);
  if (big) {
    k_out_b<<<dim3(2048), dim3(512), 0, stream>>>(xb, (u16*)(ws + WS_WB),
                                                  tacc, weight, bias, out);
  } else {
    k_out_f<<<dim3(2048), dim3(512), 0, stream>>>(x, (u16*)(ws + WS_WB),
                                                  tacc, weight, bias, out);
  }
}

// Round 6
// 212.188 us; speedup vs baseline: 1.3187x; 1.3187x over previous
//
#include <hip/hip_runtime.h>
#include <hip/hip_bf16.h>

// DecorrelatedBatchNorm1d (ZCA whitening), B=65536, F=512, fp32 in/out.
// Big-ws pipeline:
//   K1 k_prep2:    xb = bf16(x) row-major + xbT = bf16(x)^T + colsum
//                  (fused; explicit 8-deep load batch for ILP; bf16 LDS transpose,
//                   pad-68 => bank-minimum both phases)
//   K2 k_cov:      S = xbT * xbT^T upper-triangle (bf16 MFMA, split-K=32, atomics)
//   K3 k_finalize: mean, E = S/(B-1) corrected - I + eps
//   K4 k_poly s0:  E2 = E@E; G = c3*E + c4*E2        (deg-4 Taylor of (I+E)^-1/2)
//   K5 k_poly s1:  W = I + c1*E + c2*E2 + E2@G -> Wb; tacc = mean^T W
//   K6 k_out_b:    out = (xb@W - tacc)*weight + bias (pure bf16 MFMA GEMM)
// Small-ws fallback: k_prep2 with xb=null + k_out_f (fp32 reg-staged A).

#define F 512
#define LDT 65536

typedef unsigned short u16;
using bf16x8 = __attribute__((ext_vector_type(8))) short;
using f32x4  = __attribute__((ext_vector_type(4))) float;

// ---- workspace layout (bytes) ----
#define WS_S      0u
#define WS_COLSUM 1048576u
#define WS_TACC   1050624u
#define WS_MEAN   1052672u
#define WS_E      1054720u
#define WS_E2     (WS_E   + 1048576u)
#define WS_EB     (WS_E2  + 1048576u)
#define WS_E2B    (WS_EB  + 524288u)
#define WS_GB     (WS_E2B + 524288u)
#define WS_WB     (WS_GB  + 524288u)
#define WS_XB     (WS_WB  + 524288u)
#define WS_NEED_BIG (WS_XB + 67108864u)

__device__ __forceinline__ u16 f2bf(float x) {
  union { float f; unsigned u; } v; v.f = x;
  return (u16)((v.u + 0x7fffu + ((v.u >> 16) & 1u)) >> 16);
}

__device__ __forceinline__ void async_cp16(const void* g, void* l) {
  __builtin_amdgcn_global_load_lds(
      (const __attribute__((address_space(1))) unsigned int*)g,
      (__attribute__((address_space(3))) unsigned int*)l, 16, 0, 0);
}

// ---- [128 rows][64 k] bf16 tile staging ----
// LDS dest linear; source pre-swizzled: LDS row r chunk c holds global chunk c^(r&7).
__device__ __forceinline__ void stage_tile(u16* dst, const u16* src, size_t stride, int t) {
#pragma unroll
  for (int q = 0; q < 4; ++q) {
    int idx = q * 256 + t;
    int c = idx >> 3, ko = idx & 7;
    async_cp16(src + (size_t)c * stride + (size_t)((ko ^ (c & 7)) << 3), dst + idx * 8);
  }
}

__device__ __forceinline__ void stage512(u16* dst, const u16* src, size_t stride, int t) {
#pragma unroll
  for (int q = 0; q < 2; ++q) {
    int idx = q * 512 + t;
    int c = idx >> 3, ko = idx & 7;
    async_cp16(src + (size_t)c * stride + (size_t)((ko ^ (c & 7)) << 3), dst + idx * 8);
  }
}

__device__ __forceinline__ void stage64(u16* dst, const u16* src, size_t stride, int t) {
#pragma unroll
  for (int q = 0; q < 2; ++q) {
    int idx = q * 256 + t;
    int r = idx >> 3, ko = idx & 7;
    async_cp16(src + (size_t)r * stride + (size_t)((ko ^ (r & 7)) << 3), dst + idx * 8);
  }
}

// 128x128 tile step, 4 waves (k_cov)
__device__ __forceinline__ void mm_step(const u16* As, const u16* Bs, int wr, int wc,
                                        int l, f32x4 acc[4][4]) {
#pragma unroll
  for (int kh = 0; kh < 2; ++kh) {
    bf16x8 a[4], b[4];
#pragma unroll
    for (int m = 0; m < 4; ++m) {
      int row = wr * 64 + m * 16 + (l & 15);
      int ch = (kh * 4 + (l >> 4)) ^ (row & 7);
      a[m] = *(const bf16x8*)(As + row * 64 + ch * 8);
    }
#pragma unroll
    for (int n = 0; n < 4; ++n) {
      int row = wc * 64 + n * 16 + (l & 15);
      int ch = (kh * 4 + (l >> 4)) ^ (row & 7);
      b[n] = *(const bf16x8*)(Bs + row * 64 + ch * 8);
    }
#pragma unroll
    for (int m = 0; m < 4; ++m)
#pragma unroll
      for (int n = 0; n < 4; ++n)
        acc[m][n] = __builtin_amdgcn_mfma_f32_16x16x32_bf16(a[m], b[n], acc[m][n], 0, 0, 0);
  }
}

// 128x128 tile step, 8 waves (k_out): wave-tile 64x32
__device__ __forceinline__ void mm_step8(const u16* As, const u16* Bs, int wr, int wc,
                                         int l, f32x4 acc[4][2]) {
#pragma unroll
  for (int kh = 0; kh < 2; ++kh) {
    bf16x8 a[4], b[2];
#pragma unroll
    for (int m = 0; m < 4; ++m) {
      int row = wr * 64 + m * 16 + (l & 15);
      int ch = (kh * 4 + (l >> 4)) ^ (row & 7);
      a[m] = *(const bf16x8*)(As + row * 64 + ch * 8);
    }
#pragma unroll
    for (int n = 0; n < 2; ++n) {
      int row = wc * 32 + n * 16 + (l & 15);
      int ch = (kh * 4 + (l >> 4)) ^ (row & 7);
      b[n] = *(const bf16x8*)(Bs + row * 64 + ch * 8);
    }
#pragma unroll
    for (int m = 0; m < 4; ++m)
#pragma unroll
      for (int n = 0; n < 2; ++n)
        acc[m][n] = __builtin_amdgcn_mfma_f32_16x16x32_bf16(a[m], b[n], acc[m][n], 0, 0, 0);
  }
}

// 64x64 tile step, 4 waves (poly)
__device__ __forceinline__ void mm64(const u16* As, const u16* Bs, int wr, int wc,
                                     int l, f32x4 acc[2][2]) {
#pragma unroll
  for (int kh = 0; kh < 2; ++kh) {
    bf16x8 a[2], b[2];
#pragma unroll
    for (int m = 0; m < 2; ++m) {
      int row = wr * 32 + m * 16 + (l & 15);
      int ch = (kh * 4 + (l >> 4)) ^ (row & 7);
      a[m] = *(const bf16x8*)(As + row * 64 + ch * 8);
    }
#pragma unroll
    for (int n = 0; n < 2; ++n) {
      int row = wc * 32 + n * 16 + (l & 15);
      int ch = (kh * 4 + (l >> 4)) ^ (row & 7);
      b[n] = *(const bf16x8*)(Bs + row * 64 + ch * 8);
    }
#pragma unroll
    for (int m = 0; m < 2; ++m)
#pragma unroll
      for (int n = 0; n < 2; ++n)
        acc[m][n] = __builtin_amdgcn_mfma_f32_16x16x32_bf16(a[m], b[n], acc[m][n], 0, 0, 0);
  }
}

// ---------------- K1: fused conv + transpose + colsum ----------------
// grid (512, 8), 256 thr; tile = 128 batch rows x 64 feats.
// Phase A: 8 float4 loads batched up-front (ILP), convert once -> xb + bf16 LDS tile.
// LDS [128][68] u16: phase-A ushort4 writes and phase-B u16 transposed reads are
// both at the 32-bank minimum (no conflicts).
// Phase B: thread (c=t&63, seg=t>>6) packs 32 batch u16 -> 4x uint4 stores to xbT.
__global__ __launch_bounds__(256) void k_prep2(const float* __restrict__ x,
                                               u16* __restrict__ xb,
                                               u16* __restrict__ xbT,
                                               float* __restrict__ colsum) {
  __shared__ __attribute__((aligned(16))) u16 tile[128 * 68];
  __shared__ float red[1024];
  const int t = threadIdx.x;
  const int r0 = blockIdx.x * 128, c0 = blockIdx.y * 64;
  const int c4 = t & 15, rg = t >> 4;
  float4 ld[8];
#pragma unroll
  for (int p = 0; p < 8; ++p) {
    int r = rg + p * 16;
    ld[p] = *(const float4*)(x + (size_t)(r0 + r) * F + c0 + c4 * 4);
  }
  float s0 = 0, s1 = 0, s2 = 0, s3 = 0;
#pragma unroll
  for (int p = 0; p < 8; ++p) {
    int r = rg + p * 16;
    s0 += ld[p].x; s1 += ld[p].y; s2 += ld[p].z; s3 += ld[p].w;
    ushort4 o;
    o.x = f2bf(ld[p].x); o.y = f2bf(ld[p].y); o.z = f2bf(ld[p].z); o.w = f2bf(ld[p].w);
    if (xb) *(ushort4*)(xb + (size_t)(r0 + r) * F + c0 + c4 * 4) = o;
    *(ushort4*)(tile + r * 68 + c4 * 4) = o;
  }
  red[rg * 64 + c4 * 4 + 0] = s0;
  red[rg * 64 + c4 * 4 + 1] = s1;
  red[rg * 64 + c4 * 4 + 2] = s2;
  red[rg * 64 + c4 * 4 + 3] = s3;
  __syncthreads();
  const int c = t & 63, seg = t >> 6;
#pragma unroll
  for (int k = 0; k < 4; ++k) {
    int rb = seg * 32 + k * 8;
    unsigned v0 = tile[(rb + 0) * 68 + c], v1 = tile[(rb + 1) * 68 + c];
    unsigned v2 = tile[(rb + 2) * 68 + c], v3 = tile[(rb + 3) * 68 + c];
    unsigned v4 = tile[(rb + 4) * 68 + c], v5 = tile[(rb + 5) * 68 + c];
    unsigned v6 = tile[(rb + 6) * 68 + c], v7 = tile[(rb + 7) * 68 + c];
    uint4 o;
    o.x = v0 | (v1 << 16);
    o.y = v2 | (v3 << 16);
    o.z = v4 | (v5 << 16);
    o.w = v6 | (v7 << 16);
    *(uint4*)(xbT + (size_t)(c0 + c) * LDT + r0 + rb) = o;
  }
  if (t < 64) {
    float s = 0;
#pragma unroll
    for (int g = 0; g < 16; ++g) s += red[g * 64 + t];
    atomicAdd(colsum + c0 + t, s);
  }
}

// ---------------- K2: S = X^T X, upper-triangle 128-tiles, split-K=32 ----------------
__global__ __launch_bounds__(256) void k_cov(const u16* __restrict__ xbT,
                                             float* __restrict__ S) {
  __shared__ __attribute__((aligned(16))) u16 As[2][128 * 64];
  __shared__ __attribute__((aligned(16))) u16 Bs[2][128 * 64];
  const int b = blockIdx.x;
  const int i = b >> 3;               // 0..39
  const int slab = (b & 7) * 4 + i / 10;
  const int tid = i % 10;
  int ta, tb;
  if (tid < 4)      { ta = 0; tb = tid; }
  else if (tid < 7) { ta = 1; tb = tid - 3; }
  else if (tid < 9) { ta = 2; tb = tid - 5; }
  else              { ta = 3; tb = 3; }
  const int a0 = ta * 128, b0 = tb * 128;
  const size_t kbase = (size_t)slab * 2048;
  const int t = threadIdx.x;
  const int l = t & 63, w = t >> 6, wr = w >> 1, wc = w & 1;
  f32x4 acc[4][4] = {};
  const u16* Abase = xbT + (size_t)a0 * LDT + kbase;
  const u16* Bbase = xbT + (size_t)b0 * LDT + kbase;
  stage_tile(As[0], Abase, LDT, t);
  stage_tile(Bs[0], Bbase, LDT, t);
  __syncthreads();
  for (int it = 0; it < 32; ++it) {
    int cur = it & 1;
    if (it < 31) {
      stage_tile(As[cur ^ 1], Abase + (it + 1) * 64, LDT, t);
      stage_tile(Bs[cur ^ 1], Bbase + (it + 1) * 64, LDT, t);
    }
    mm_step(As[cur], Bs[cur], wr, wc, l, acc);
    __syncthreads();
  }
#pragma unroll
  for (int m = 0; m < 4; ++m) {
    int rg = a0 + wr * 64 + m * 16 + ((l >> 4) << 2);
#pragma unroll
    for (int n = 0; n < 4; ++n) {
      int cg = b0 + wc * 64 + n * 16 + (l & 15);
#pragma unroll
      for (int r = 0; r < 4; ++r)
        atomicAdd(S + (size_t)(rg + r) * F + cg, acc[m][n][r]);
    }
  }
}

// ---------------- K3: finalize mean + E = cov - I ----------------
__global__ __launch_bounds__(256) void k_finalize(const float* __restrict__ S,
                                                  const float* __restrict__ colsum,
                                                  float* __restrict__ mean,
                                                  float* __restrict__ E,
                                                  u16* __restrict__ Eb) {
  int gid = blockIdx.x * 256 + threadIdx.x;
  int i = gid >> 9, j = gid & 511;
  float mi = colsum[i] * (1.0f / 65536.0f);
  float mj = colsum[j] * (1.0f / 65536.0f);
  float sv = ((i >> 7) <= (j >> 7)) ? S[(size_t)i * F + j] : S[(size_t)j * F + i];
  float cov = (sv - 65536.0f * mi * mj) * (1.0f / 65535.0f);
  float e = cov + ((i == j) ? (0.001f - 1.0f) : 0.0f);
  E[gid] = e;
  Eb[gid] = f2bf(e);
  if (gid < F) mean[gid] = colsum[gid] * (1.0f / 65536.0f);
}

// ---------------- K4/K5: degree-4 Taylor of (I+E)^(-1/2) ----------------
__global__ __launch_bounds__(256) void k_poly(char* __restrict__ wsb, int stg) {
  __shared__ __attribute__((aligned(16))) u16 As[2][64 * 64];
  __shared__ __attribute__((aligned(16))) u16 Bs[2][64 * 64];
  const int tile = blockIdx.x;
  const int tr = tile >> 3, tc = tile & 7;
  const int r0 = tr * 64, c0 = tc * 64;
  const u16* Eb  = (const u16*)(wsb + WS_EB);
  const u16* E2b = (const u16*)(wsb + WS_E2B);
  const u16* Gb  = (const u16*)(wsb + WS_GB);
  const u16* Ab; const u16* Bb;
  if (stg == 0) { Ab = Eb;  Bb = Eb; }
  else          { Ab = E2b; Bb = Gb; }
  const int t = threadIdx.x;
  const int l = t & 63, w = t >> 6, wr = w >> 1, wc = w & 1;
  f32x4 acc[2][2] = {};
  stage64(As[0], Ab + (size_t)r0 * F, F, t);
  stage64(Bs[0], Bb + (size_t)c0 * F, F, t);
  __syncthreads();
  for (int it = 0; it < 8; ++it) {
    int cur = it & 1;
    if (it < 7) {
      stage64(As[cur ^ 1], Ab + (size_t)r0 * F + (it + 1) * 64, F, t);
      stage64(Bs[cur ^ 1], Bb + (size_t)c0 * F + (it + 1) * 64, F, t);
    }
    mm64(As[cur], Bs[cur], wr, wc, l, acc);
    __syncthreads();
  }
  const float* Ef  = (const float*)(wsb + WS_E);
  const float* E2f = (const float*)(wsb + WS_E2);
  const float* mean = (const float*)(wsb + WS_MEAN);
  float* tacc = (float*)(wsb + WS_TACC);
  const float c1 = -0.5f, c2 = 0.375f, c3 = -0.3125f, c4 = 35.0f / 128.0f;
#pragma unroll
  for (int n = 0; n < 2; ++n) {
    int cg = c0 + wc * 32 + n * 16 + (l & 15);
    float ts = 0.0f;
#pragma unroll
    for (int m = 0; m < 2; ++m) {
#pragma unroll
      for (int r = 0; r < 4; ++r) {
        int rg = r0 + wr * 32 + m * 16 + ((l >> 4) << 2) + r;
        size_t o = (size_t)rg * F + cg;
        float v = acc[m][n][r];
        if (stg == 0) {
          ((float*)(wsb + WS_E2))[o] = v;
          ((u16*)(wsb + WS_E2B))[o] = f2bf(v);
          ((u16*)(wsb + WS_GB))[o]  = f2bf(c3 * Ef[o] + c4 * v);
        } else {
          float wv = c1 * Ef[o] + c2 * E2f[o] + v + ((rg == cg) ? 1.0f : 0.0f);
          ((u16*)(wsb + WS_WB))[o] = f2bf(wv);
          ts += mean[rg] * wv;
        }
      }
    }
    if (stg == 1) atomicAdd(tacc + cg, ts);
  }
}

// ---------------- K6: out = (xb@W - tacc)*w + b  (pure bf16 GEMM) --------
__global__ __launch_bounds__(512) void k_out_b(const u16* __restrict__ xb,
                                               const u16* __restrict__ Wb,
                                               const float* __restrict__ tacc,
                                               const float* __restrict__ wgt,
                                               const float* __restrict__ bias,
                                               float* __restrict__ out) {
  __shared__ __attribute__((aligned(16))) u16 As[2][128 * 64];
  __shared__ __attribute__((aligned(16))) u16 Bs[2][128 * 64];
  const int b = blockIdx.x;
  const int i = b >> 3;
  const int rt = (b & 7) * 64 + (i >> 2), ct = i & 3;
  const int i0 = rt * 128, j0 = ct * 128;
  const int t = threadIdx.x;
  const int l = t & 63, w = t >> 6, wr = w >> 2, wc = w & 3;
  f32x4 acc[4][2] = {};
  const u16* Abase = xb + (size_t)i0 * F;
  const u16* Bbase = Wb + (size_t)j0 * F;
  stage512(As[0], Abase, F, t);
  stage512(Bs[0], Bbase, F, t);
  __syncthreads();
  for (int it = 0; it < 8; ++it) {
    int cur = it & 1;
    if (it < 7) {
      stage512(As[cur ^ 1], Abase + (it + 1) * 64, F, t);
      stage512(Bs[cur ^ 1], Bbase + (it + 1) * 64, F, t);
    }
    mm_step8(As[cur], Bs[cur], wr, wc, l, acc);
    __syncthreads();
  }
#pragma unroll
  for (int n = 0; n < 2; ++n) {
    int cg = j0 + wc * 32 + n * 16 + (l & 15);
    float mv = tacc[cg];
    float wv = wgt[cg], bv = bias[cg];
#pragma unroll
    for (int m = 0; m < 4; ++m) {
      int rb = i0 + wr * 64 + m * 16 + ((l >> 4) << 2);
#pragma unroll
      for (int r = 0; r < 4; ++r) {
        size_t o = (size_t)(rb + r) * F + cg;
        out[o] = (acc[m][n][r] - mv) * wv + bv;
      }
    }
  }
}

// ---------------- small-ws fallback: fp32 reg-staged A ----------------
__global__ __launch_bounds__(512) void k_out_f(const float* __restrict__ x,
                                               const u16* __restrict__ Wb,
                                               const float* __restrict__ tacc,
                                               const float* __restrict__ wgt,
                                               const float* __restrict__ bias,
                                               float* __restrict__ out) {
  __shared__ __attribute__((aligned(16))) u16 As[2][128 * 64];
  __shared__ __attribute__((aligned(16))) u16 Bs[2][128 * 64];
  const int b = blockIdx.x;
  const int i = b >> 3;
  const int rt = (b & 7) * 64 + (i >> 2), ct = i & 3;
  const int i0 = rt * 128, j0 = ct * 128;
  const int t = threadIdx.x;
  const int l = t & 63, w = t >> 6, wr = w >> 2, wc = w & 3;
  f32x4 acc[4][2] = {};
  float4 ld[4];
  stage512(Bs[0], Wb + (size_t)j0 * F, F, t);
#pragma unroll
  for (int q = 0; q < 4; ++q) {
    int idx = q * 512 + t, r = idx >> 4, kc = idx & 15;
    ld[q] = *(const float4*)(x + (size_t)(i0 + r) * F + kc * 4);
  }
#pragma unroll
  for (int q = 0; q < 4; ++q) {
    int idx = q * 512 + t, r = idx >> 4, kc = idx & 15;
    ushort4 o;
    o.x = f2bf(ld[q].x); o.y = f2bf(ld[q].y); o.z = f2bf(ld[q].z); o.w = f2bf(ld[q].w);
    *(ushort4*)(As[0] + r * 64 + (((kc >> 1) ^ (r & 7)) << 3) + ((kc & 1) << 2)) = o;
  }
  __syncthreads();
  for (int it = 0; it < 8; ++it) {
    int cur = it & 1;
    if (it < 7) {
      int kk = (it + 1) * 64;
#pragma unroll
      for (int q = 0; q < 4; ++q) {
        int idx = q * 512 + t, r = idx >> 4, kc = idx & 15;
        ld[q] = *(const float4*)(x + (size_t)(i0 + r) * F + kk + kc * 4);
      }
      stage512(Bs[cur ^ 1], Wb + (size_t)j0 * F + kk, F, t);
    }
    mm_step8(As[cur], Bs[cur], wr, wc, l, acc);
    if (it < 7) {
#pragma unroll
      for (int q = 0; q < 4; ++q) {
        int idx = q * 512 + t, r = idx >> 4, kc = idx & 15;
        ushort4 o;
        o.x = f2bf(ld[q].x); o.y = f2bf(ld[q].y); o.z = f2bf(ld[q].z); o.w = f2bf(ld[q].w);
        *(ushort4*)(As[cur ^ 1] + r * 64 + (((kc >> 1) ^ (r & 7)) << 3) + ((kc & 1) << 2)) = o;
      }
    }
    __syncthreads();
  }
#pragma unroll
  for (int n = 0; n < 2; ++n) {
    int cg = j0 + wc * 32 + n * 16 + (l & 15);
    float mv = tacc[cg];
    float wv = wgt[cg], bv = bias[cg];
#pragma unroll
    for (int m = 0; m < 4; ++m) {
      int rb = i0 + wr * 64 + m * 16 + ((l >> 4) << 2);
#pragma unroll
      for (int r = 0; r < 4; ++r) {
        size_t o = (size_t)(rb + r) * F + cg;
        out[o] = (acc[m][n][r] - mv) * wv + bv;
      }
    }
  }
}

extern "C" void kernel_launch(void* const* d_in, const int* in_sizes, int n_in,
                              void* d_out, int out_size, void* d_ws, size_t ws_size,
                              hipStream_t stream) {
  (void)in_sizes; (void)n_in; (void)out_size;
  const float* x      = (const float*)d_in[0];
  const float* weight = (const float*)d_in[1];
  const float* bias   = (const float*)d_in[2];
  float* out = (float*)d_out;
  char* ws   = (char*)d_ws;
  // xbT (64 MiB) overlays d_out; dead before k_out writes d_out.
  u16* xbT = (u16*)d_out;
  const bool big = ws_size >= (size_t)WS_NEED_BIG;
  u16* xb = big ? (u16*)(ws + WS_XB) : nullptr;

  float* S      = (float*)(ws + WS_S);
  float* colsum = (float*)(ws + WS_COLSUM);
  float* tacc   = (float*)(ws + WS_TACC);
  float* mean   = (float*)(ws + WS_MEAN);

  hipMemsetAsync(ws, 0, WS_MEAN, stream);  // zero S + colsum + tacc

  k_prep2<<<dim3(512, 8), dim3(256), 0, stream>>>(x, xb, xbT, colsum);
  k_cov<<<dim3(320), dim3(256), 0, stream>>>(xbT, S);
  k_finalize<<<dim3(1024), dim3(256), 0, stream>>>(S, colsum, mean,
                                                   (float*)(ws + WS_E),
                                                   (u16*)(ws + WS_EB));
  k_poly<<<dim3(64), dim3(256), 0, stream>>>(ws, 0);
  k_poly<<<dim3(64), dim3(256), 0, stream>>>(ws, 1);
  if (big) {
    k_out_b<<<dim3(2048), dim3(512), 0, stream>>>(xb, (u16*)(ws + WS_WB),
                                                  tacc, weight, bias, out);
  } else {
    k_out_f<<<dim3(2048), dim3(512), 0, stream>>>(x, (u16*)(ws + WS_WB),
                                                  tacc, weight, bias, out);
  }
}

// Round 7
// 207.431 us; speedup vs baseline: 1.3490x; 1.0229x over previous
//
#include <hip/hip_runtime.h>
#include <hip/hip_bf16.h>

// DecorrelatedBatchNorm1d (ZCA whitening), B=65536, F=512, fp32 in/out.
// Big-ws pipeline:
//   K1 k_prep2:    xb = bf16(x) row-major + xbT = bf16(x)^T + colsum
//                  (x staged via global_load_lds -> deep async queue, no VGPR
//                   pressure; XOR-swizzled source + un-XOR ds_read_b128)
//   K2 k_cov:      S = xbT * xbT^T upper-triangle (bf16 MFMA, split-K=32, atomics)
//   K3 k_finalize: mean, E = S/(B-1) corrected - I + eps
//   K4 k_poly s0:  E2 = E@E; G = c3*E + c4*E2        (deg-4 Taylor of (I+E)^-1/2)
//   K5 k_poly s1:  W = I + c1*E + c2*E2 + E2@G -> Wb; tacc = mean^T W
//   K6 k_out_b:    out = (xb@W - tacc)*weight + bias (pure bf16 MFMA GEMM,
//                   nontemporal out stores)
// Small-ws fallback: k_prep2 with xb=null + k_out_f (fp32 reg-staged A).

#define F 512
#define LDT 65536

typedef unsigned short u16;
using bf16x8 = __attribute__((ext_vector_type(8))) short;
using f32x4  = __attribute__((ext_vector_type(4))) float;

// ---- workspace layout (bytes) ----
#define WS_S      0u
#define WS_COLSUM 1048576u
#define WS_TACC   1050624u
#define WS_MEAN   1052672u
#define WS_E      1054720u
#define WS_E2     (WS_E   + 1048576u)
#define WS_EB     (WS_E2  + 1048576u)
#define WS_E2B    (WS_EB  + 524288u)
#define WS_GB     (WS_E2B + 524288u)
#define WS_WB     (WS_GB  + 524288u)
#define WS_XB     (WS_WB  + 524288u)
#define WS_NEED_BIG (WS_XB + 67108864u)

__device__ __forceinline__ u16 f2bf(float x) {
  union { float f; unsigned u; } v; v.f = x;
  return (u16)((v.u + 0x7fffu + ((v.u >> 16) & 1u)) >> 16);
}

__device__ __forceinline__ void async_cp16(const void* g, void* l) {
  __builtin_amdgcn_global_load_lds(
      (const __attribute__((address_space(1))) unsigned int*)g,
      (__attribute__((address_space(3))) unsigned int*)l, 16, 0, 0);
}

// ---- [128 rows][64 k] bf16 tile staging ----
// LDS dest linear; source pre-swizzled: LDS row r chunk c holds global chunk c^(r&7).
__device__ __forceinline__ void stage_tile(u16* dst, const u16* src, size_t stride, int t) {
#pragma unroll
  for (int q = 0; q < 4; ++q) {
    int idx = q * 256 + t;
    int c = idx >> 3, ko = idx & 7;
    async_cp16(src + (size_t)c * stride + (size_t)((ko ^ (c & 7)) << 3), dst + idx * 8);
  }
}

__device__ __forceinline__ void stage512(u16* dst, const u16* src, size_t stride, int t) {
#pragma unroll
  for (int q = 0; q < 2; ++q) {
    int idx = q * 512 + t;
    int c = idx >> 3, ko = idx & 7;
    async_cp16(src + (size_t)c * stride + (size_t)((ko ^ (c & 7)) << 3), dst + idx * 8);
  }
}

__device__ __forceinline__ void stage64(u16* dst, const u16* src, size_t stride, int t) {
#pragma unroll
  for (int q = 0; q < 2; ++q) {
    int idx = q * 256 + t;
    int r = idx >> 3, ko = idx & 7;
    async_cp16(src + (size_t)r * stride + (size_t)((ko ^ (r & 7)) << 3), dst + idx * 8);
  }
}

// 128x128 tile step, 4 waves (k_cov)
__device__ __forceinline__ void mm_step(const u16* As, const u16* Bs, int wr, int wc,
                                        int l, f32x4 acc[4][4]) {
#pragma unroll
  for (int kh = 0; kh < 2; ++kh) {
    bf16x8 a[4], b[4];
#pragma unroll
    for (int m = 0; m < 4; ++m) {
      int row = wr * 64 + m * 16 + (l & 15);
      int ch = (kh * 4 + (l >> 4)) ^ (row & 7);
      a[m] = *(const bf16x8*)(As + row * 64 + ch * 8);
    }
#pragma unroll
    for (int n = 0; n < 4; ++n) {
      int row = wc * 64 + n * 16 + (l & 15);
      int ch = (kh * 4 + (l >> 4)) ^ (row & 7);
      b[n] = *(const bf16x8*)(Bs + row * 64 + ch * 8);
    }
#pragma unroll
    for (int m = 0; m < 4; ++m)
#pragma unroll
      for (int n = 0; n < 4; ++n)
        acc[m][n] = __builtin_amdgcn_mfma_f32_16x16x32_bf16(a[m], b[n], acc[m][n], 0, 0, 0);
  }
}

// 128x128 tile step, 8 waves (k_out): wave-tile 64x32
__device__ __forceinline__ void mm_step8(const u16* As, const u16* Bs, int wr, int wc,
                                         int l, f32x4 acc[4][2]) {
#pragma unroll
  for (int kh = 0; kh < 2; ++kh) {
    bf16x8 a[4], b[2];
#pragma unroll
    for (int m = 0; m < 4; ++m) {
      int row = wr * 64 + m * 16 + (l & 15);
      int ch = (kh * 4 + (l >> 4)) ^ (row & 7);
      a[m] = *(const bf16x8*)(As + row * 64 + ch * 8);
    }
#pragma unroll
    for (int n = 0; n < 2; ++n) {
      int row = wc * 32 + n * 16 + (l & 15);
      int ch = (kh * 4 + (l >> 4)) ^ (row & 7);
      b[n] = *(const bf16x8*)(Bs + row * 64 + ch * 8);
    }
#pragma unroll
    for (int m = 0; m < 4; ++m)
#pragma unroll
      for (int n = 0; n < 2; ++n)
        acc[m][n] = __builtin_amdgcn_mfma_f32_16x16x32_bf16(a[m], b[n], acc[m][n], 0, 0, 0);
  }
}

// 64x64 tile step, 4 waves (poly)
__device__ __forceinline__ void mm64(const u16* As, const u16* Bs, int wr, int wc,
                                     int l, f32x4 acc[2][2]) {
#pragma unroll
  for (int kh = 0; kh < 2; ++kh) {
    bf16x8 a[2], b[2];
#pragma unroll
    for (int m = 0; m < 2; ++m) {
      int row = wr * 32 + m * 16 + (l & 15);
      int ch = (kh * 4 + (l >> 4)) ^ (row & 7);
      a[m] = *(const bf16x8*)(As + row * 64 + ch * 8);
    }
#pragma unroll
    for (int n = 0; n < 2; ++n) {
      int row = wc * 32 + n * 16 + (l & 15);
      int ch = (kh * 4 + (l >> 4)) ^ (row & 7);
      b[n] = *(const bf16x8*)(Bs + row * 64 + ch * 8);
    }
#pragma unroll
    for (int m = 0; m < 2; ++m)
#pragma unroll
      for (int n = 0; n < 2; ++n)
        acc[m][n] = __builtin_amdgcn_mfma_f32_16x16x32_bf16(a[m], b[n], acc[m][n], 0, 0, 0);
  }
}

// ---------------- K1: fused conv + transpose + colsum ----------------
// grid (512, 8), 256 thr; tile = 128 batch rows x 64 feats.
// Stage: 8 async_cp16/thread stage the fp32 tile into LDS [128][16 chunks],
//   linear dest, source chunk pre-XOR'd (c ^ (r&7)) -> read-back is conflict-free.
// Phase A: ds_read_b128 un-XOR'd, convert once -> colsum + xb + bf16 tile2 [128][68].
// Phase B: transposed u16 reads from tile2, pack -> 16B xbT stores.
__global__ __launch_bounds__(256) void k_prep2(const float* __restrict__ x,
                                               u16* __restrict__ xb,
                                               u16* __restrict__ xbT,
                                               float* __restrict__ colsum) {
  __shared__ __attribute__((aligned(16))) float tileF[128 * 64];
  __shared__ __attribute__((aligned(16))) u16 tile[128 * 68];
  __shared__ float red[1024];
  const int t = threadIdx.x;
  const int r0 = blockIdx.x * 128, c0 = blockIdx.y * 64;
  // ---- stage x tile via global_load_lds (deep async queue, no VGPRs) ----
#pragma unroll
  for (int q = 0; q < 8; ++q) {
    int idx = q * 256 + t;
    int r = idx >> 4, c = idx & 15;                 // chunk = 16B = 4 floats
    async_cp16(x + (size_t)(r0 + r) * F + c0 + ((c ^ (r & 7)) << 2),
               tileF + idx * 4);
  }
  __syncthreads();
  // ---- phase A: read back, convert, colsum ----
  const int c4 = t & 15, rg = t >> 4;
  const int cc = c4 ^ (rg & 7);                     // constant un-XOR per thread
  float s0 = 0, s1 = 0, s2 = 0, s3 = 0;
#pragma unroll
  for (int p = 0; p < 8; ++p) {
    int r = rg + p * 16;                            // r&7 == rg&7 (16 = 0 mod 8)
    float4 v = *(const float4*)(tileF + r * 64 + cc * 4);
    s0 += v.x; s1 += v.y; s2 += v.z; s3 += v.w;
    ushort4 o;
    o.x = f2bf(v.x); o.y = f2bf(v.y); o.z = f2bf(v.z); o.w = f2bf(v.w);
    if (xb) *(ushort4*)(xb + (size_t)(r0 + r) * F + c0 + c4 * 4) = o;
    *(ushort4*)(tile + r * 68 + c4 * 4) = o;
  }
  red[rg * 64 + c4 * 4 + 0] = s0;
  red[rg * 64 + c4 * 4 + 1] = s1;
  red[rg * 64 + c4 * 4 + 2] = s2;
  red[rg * 64 + c4 * 4 + 3] = s3;
  __syncthreads();
  // ---- phase B: transpose out of tile2 ----
  const int c = t & 63, seg = t >> 6;
#pragma unroll
  for (int k = 0; k < 4; ++k) {
    int rb = seg * 32 + k * 8;
    unsigned v0 = tile[(rb + 0) * 68 + c], v1 = tile[(rb + 1) * 68 + c];
    unsigned v2 = tile[(rb + 2) * 68 + c], v3 = tile[(rb + 3) * 68 + c];
    unsigned v4 = tile[(rb + 4) * 68 + c], v5 = tile[(rb + 5) * 68 + c];
    unsigned v6 = tile[(rb + 6) * 68 + c], v7 = tile[(rb + 7) * 68 + c];
    uint4 o;
    o.x = v0 | (v1 << 16);
    o.y = v2 | (v3 << 16);
    o.z = v4 | (v5 << 16);
    o.w = v6 | (v7 << 16);
    *(uint4*)(xbT + (size_t)(c0 + c) * LDT + r0 + rb) = o;
  }
  if (t < 64) {
    float s = 0;
#pragma unroll
    for (int g = 0; g < 16; ++g) s += red[g * 64 + t];
    atomicAdd(colsum + c0 + t, s);
  }
}

// ---------------- K2: S = X^T X, upper-triangle 128-tiles, split-K=32 ----------------
__global__ __launch_bounds__(256) void k_cov(const u16* __restrict__ xbT,
                                             float* __restrict__ S) {
  __shared__ __attribute__((aligned(16))) u16 As[2][128 * 64];
  __shared__ __attribute__((aligned(16))) u16 Bs[2][128 * 64];
  const int b = blockIdx.x;
  const int i = b >> 3;               // 0..39
  const int slab = (b & 7) * 4 + i / 10;
  const int tid = i % 10;
  int ta, tb;
  if (tid < 4)      { ta = 0; tb = tid; }
  else if (tid < 7) { ta = 1; tb = tid - 3; }
  else if (tid < 9) { ta = 2; tb = tid - 5; }
  else              { ta = 3; tb = 3; }
  const int a0 = ta * 128, b0 = tb * 128;
  const size_t kbase = (size_t)slab * 2048;
  const int t = threadIdx.x;
  const int l = t & 63, w = t >> 6, wr = w >> 1, wc = w & 1;
  f32x4 acc[4][4] = {};
  const u16* Abase = xbT + (size_t)a0 * LDT + kbase;
  const u16* Bbase = xbT + (size_t)b0 * LDT + kbase;
  stage_tile(As[0], Abase, LDT, t);
  stage_tile(Bs[0], Bbase, LDT, t);
  __syncthreads();
  for (int it = 0; it < 32; ++it) {
    int cur = it & 1;
    if (it < 31) {
      stage_tile(As[cur ^ 1], Abase + (it + 1) * 64, LDT, t);
      stage_tile(Bs[cur ^ 1], Bbase + (it + 1) * 64, LDT, t);
    }
    mm_step(As[cur], Bs[cur], wr, wc, l, acc);
    __syncthreads();
  }
#pragma unroll
  for (int m = 0; m < 4; ++m) {
    int rg = a0 + wr * 64 + m * 16 + ((l >> 4) << 2);
#pragma unroll
    for (int n = 0; n < 4; ++n) {
      int cg = b0 + wc * 64 + n * 16 + (l & 15);
#pragma unroll
      for (int r = 0; r < 4; ++r)
        atomicAdd(S + (size_t)(rg + r) * F + cg, acc[m][n][r]);
    }
  }
}

// ---------------- K3: finalize mean + E = cov - I ----------------
__global__ __launch_bounds__(256) void k_finalize(const float* __restrict__ S,
                                                  const float* __restrict__ colsum,
                                                  float* __restrict__ mean,
                                                  float* __restrict__ E,
                                                  u16* __restrict__ Eb) {
  int gid = blockIdx.x * 256 + threadIdx.x;
  int i = gid >> 9, j = gid & 511;
  float mi = colsum[i] * (1.0f / 65536.0f);
  float mj = colsum[j] * (1.0f / 65536.0f);
  float sv = ((i >> 7) <= (j >> 7)) ? S[(size_t)i * F + j] : S[(size_t)j * F + i];
  float cov = (sv - 65536.0f * mi * mj) * (1.0f / 65535.0f);
  float e = cov + ((i == j) ? (0.001f - 1.0f) : 0.0f);
  E[gid] = e;
  Eb[gid] = f2bf(e);
  if (gid < F) mean[gid] = colsum[gid] * (1.0f / 65536.0f);
}

// ---------------- K4/K5: degree-4 Taylor of (I+E)^(-1/2) ----------------
__global__ __launch_bounds__(256) void k_poly(char* __restrict__ wsb, int stg) {
  __shared__ __attribute__((aligned(16))) u16 As[2][64 * 64];
  __shared__ __attribute__((aligned(16))) u16 Bs[2][64 * 64];
  const int tile = blockIdx.x;
  const int tr = tile >> 3, tc = tile & 7;
  const int r0 = tr * 64, c0 = tc * 64;
  const u16* Eb  = (const u16*)(wsb + WS_EB);
  const u16* E2b = (const u16*)(wsb + WS_E2B);
  const u16* Gb  = (const u16*)(wsb + WS_GB);
  const u16* Ab; const u16* Bb;
  if (stg == 0) { Ab = Eb;  Bb = Eb; }
  else          { Ab = E2b; Bb = Gb; }
  const int t = threadIdx.x;
  const int l = t & 63, w = t >> 6, wr = w >> 1, wc = w & 1;
  f32x4 acc[2][2] = {};
  stage64(As[0], Ab + (size_t)r0 * F, F, t);
  stage64(Bs[0], Bb + (size_t)c0 * F, F, t);
  __syncthreads();
  for (int it = 0; it < 8; ++it) {
    int cur = it & 1;
    if (it < 7) {
      stage64(As[cur ^ 1], Ab + (size_t)r0 * F + (it + 1) * 64, F, t);
      stage64(Bs[cur ^ 1], Bb + (size_t)c0 * F + (it + 1) * 64, F, t);
    }
    mm64(As[cur], Bs[cur], wr, wc, l, acc);
    __syncthreads();
  }
  const float* Ef  = (const float*)(wsb + WS_E);
  const float* E2f = (const float*)(wsb + WS_E2);
  const float* mean = (const float*)(wsb + WS_MEAN);
  float* tacc = (float*)(wsb + WS_TACC);
  const float c1 = -0.5f, c2 = 0.375f, c3 = -0.3125f, c4 = 35.0f / 128.0f;
#pragma unroll
  for (int n = 0; n < 2; ++n) {
    int cg = c0 + wc * 32 + n * 16 + (l & 15);
    float ts = 0.0f;
#pragma unroll
    for (int m = 0; m < 2; ++m) {
#pragma unroll
      for (int r = 0; r < 4; ++r) {
        int rg = r0 + wr * 32 + m * 16 + ((l >> 4) << 2) + r;
        size_t o = (size_t)rg * F + cg;
        float v = acc[m][n][r];
        if (stg == 0) {
          ((float*)(wsb + WS_E2))[o] = v;
          ((u16*)(wsb + WS_E2B))[o] = f2bf(v);
          ((u16*)(wsb + WS_GB))[o]  = f2bf(c3 * Ef[o] + c4 * v);
        } else {
          float wv = c1 * Ef[o] + c2 * E2f[o] + v + ((rg == cg) ? 1.0f : 0.0f);
          ((u16*)(wsb + WS_WB))[o] = f2bf(wv);
          ts += mean[rg] * wv;
        }
      }
    }
    if (stg == 1) atomicAdd(tacc + cg, ts);
  }
}

// ---------------- K6: out = (xb@W - tacc)*w + b  (pure bf16 GEMM) --------
__global__ __launch_bounds__(512) void k_out_b(const u16* __restrict__ xb,
                                               const u16* __restrict__ Wb,
                                               const float* __restrict__ tacc,
                                               const float* __restrict__ wgt,
                                               const float* __restrict__ bias,
                                               float* __restrict__ out) {
  __shared__ __attribute__((aligned(16))) u16 As[2][128 * 64];
  __shared__ __attribute__((aligned(16))) u16 Bs[2][128 * 64];
  const int b = blockIdx.x;
  const int i = b >> 3;
  const int rt = (b & 7) * 64 + (i >> 2), ct = i & 3;
  const int i0 = rt * 128, j0 = ct * 128;
  const int t = threadIdx.x;
  const int l = t & 63, w = t >> 6, wr = w >> 2, wc = w & 3;
  f32x4 acc[4][2] = {};
  const u16* Abase = xb + (size_t)i0 * F;
  const u16* Bbase = Wb + (size_t)j0 * F;
  stage512(As[0], Abase, F, t);
  stage512(Bs[0], Bbase, F, t);
  __syncthreads();
  for (int it = 0; it < 8; ++it) {
    int cur = it & 1;
    if (it < 7) {
      stage512(As[cur ^ 1], Abase + (it + 1) * 64, F, t);
      stage512(Bs[cur ^ 1], Bbase + (it + 1) * 64, F, t);
    }
    mm_step8(As[cur], Bs[cur], wr, wc, l, acc);
    __syncthreads();
  }
#pragma unroll
  for (int n = 0; n < 2; ++n) {
    int cg = j0 + wc * 32 + n * 16 + (l & 15);
    float mv = tacc[cg];
    float wv = wgt[cg], bv = bias[cg];
#pragma unroll
    for (int m = 0; m < 4; ++m) {
      int rb = i0 + wr * 64 + m * 16 + ((l >> 4) << 2);
#pragma unroll
      for (int r = 0; r < 4; ++r) {
        size_t o = (size_t)(rb + r) * F + cg;
        __builtin_nontemporal_store((acc[m][n][r] - mv) * wv + bv, out + o);
      }
    }
  }
}

// ---------------- small-ws fallback: fp32 reg-staged A ----------------
__global__ __launch_bounds__(512) void k_out_f(const float* __restrict__ x,
                                               const u16* __restrict__ Wb,
                                               const float* __restrict__ tacc,
                                               const float* __restrict__ wgt,
                                               const float* __restrict__ bias,
                                               float* __restrict__ out) {
  __shared__ __attribute__((aligned(16))) u16 As[2][128 * 64];
  __shared__ __attribute__((aligned(16))) u16 Bs[2][128 * 64];
  const int b = blockIdx.x;
  const int i = b >> 3;
  const int rt = (b & 7) * 64 + (i >> 2), ct = i & 3;
  const int i0 = rt * 128, j0 = ct * 128;
  const int t = threadIdx.x;
  const int l = t & 63, w = t >> 6, wr = w >> 2, wc = w & 3;
  f32x4 acc[4][2] = {};
  float4 ld[4];
  stage512(Bs[0], Wb + (size_t)j0 * F, F, t);
#pragma unroll
  for (int q = 0; q < 4; ++q) {
    int idx = q * 512 + t, r = idx >> 4, kc = idx & 15;
    ld[q] = *(const float4*)(x + (size_t)(i0 + r) * F + kc * 4);
  }
#pragma unroll
  for (int q = 0; q < 4; ++q) {
    int idx = q * 512 + t, r = idx >> 4, kc = idx & 15;
    ushort4 o;
    o.x = f2bf(ld[q].x); o.y = f2bf(ld[q].y); o.z = f2bf(ld[q].z); o.w = f2bf(ld[q].w);
    *(ushort4*)(As[0] + r * 64 + (((kc >> 1) ^ (r & 7)) << 3) + ((kc & 1) << 2)) = o;
  }
  __syncthreads();
  for (int it = 0; it < 8; ++it) {
    int cur = it & 1;
    if (it < 7) {
      int kk = (it + 1) * 64;
#pragma unroll
      for (int q = 0; q < 4; ++q) {
        int idx = q * 512 + t, r = idx >> 4, kc = idx & 15;
        ld[q] = *(const float4*)(x + (size_t)(i0 + r) * F + kk + kc * 4);
      }
      stage512(Bs[cur ^ 1], Wb + (size_t)j0 * F + kk, F, t);
    }
    mm_step8(As[cur], Bs[cur], wr, wc, l, acc);
    if (it < 7) {
#pragma unroll
      for (int q = 0; q < 4; ++q) {
        int idx = q * 512 + t, r = idx >> 4, kc = idx & 15;
        ushort4 o;
        o.x = f2bf(ld[q].x); o.y = f2bf(ld[q].y); o.z = f2bf(ld[q].z); o.w = f2bf(ld[q].w);
        *(ushort4*)(As[cur ^ 1] + r * 64 + (((kc >> 1) ^ (r & 7)) << 3) + ((kc & 1) << 2)) = o;
      }
    }
    __syncthreads();
  }
#pragma unroll
  for (int n = 0; n < 2; ++n) {
    int cg = j0 + wc * 32 + n * 16 + (l & 15);
    float mv = tacc[cg];
    float wv = wgt[cg], bv = bias[cg];
#pragma unroll
    for (int m = 0; m < 4; ++m) {
      int rb = i0 + wr * 64 + m * 16 + ((l >> 4) << 2);
#pragma unroll
      for (int r = 0; r < 4; ++r) {
        size_t o = (size_t)(rb + r) * F + cg;
        __builtin_nontemporal_store((acc[m][n][r] - mv) * wv + bv, out + o);
      }
    }
  }
}

extern "C" void kernel_launch(void* const* d_in, const int* in_sizes, int n_in,
                              void* d_out, int out_size, void* d_ws, size_t ws_size,
                              hipStream_t stream) {
  (void)in_sizes; (void)n_in; (void)out_size;
  const float* x      = (const float*)d_in[0];
  const float* weight = (const float*)d_in[1];
  const float* bias   = (const float*)d_in[2];
  float* out = (float*)d_out;
  char* ws   = (char*)d_ws;
  // xbT (64 MiB) overlays d_out; dead before k_out writes d_out.
  u16* xbT = (u16*)d_out;
  const bool big = ws_size >= (size_t)WS_NEED_BIG;
  u16* xb = big ? (u16*)(ws + WS_XB) : nullptr;

  float* S      = (float*)(ws + WS_S);
  float* colsum = (float*)(ws + WS_COLSUM);
  float* tacc   = (float*)(ws + WS_TACC);
  float* mean   = (float*)(ws + WS_MEAN);

  hipMemsetAsync(ws, 0, WS_MEAN, stream);  // zero S + colsum + tacc

  k_prep2<<<dim3(512, 8), dim3(256), 0, stream>>>(x, xb, xbT, colsum);
  k_cov<<<dim3(320), dim3(256), 0, stream>>>(xbT, S);
  k_finalize<<<dim3(1024), dim3(256), 0, stream>>>(S, colsum, mean,
                                                   (float*)(ws + WS_E),
                                                   (u16*)(ws + WS_EB));
  k_poly<<<dim3(64), dim3(256), 0, stream>>>(ws, 0);
  k_poly<<<dim3(64), dim3(256), 0, stream>>>(ws, 1);
  if (big) {
    k_out_b<<<dim3(2048), dim3(512), 0, stream>>>(xb, (u16*)(ws + WS_WB),
                                                  tacc, weight, bias, out);
  } else {
    k_out_f<<<dim3(2048), dim3(512), 0, stream>>>(x, (u16*)(ws + WS_WB),
                                                  tacc, weight, bias, out);
  }
}

// Round 8
// 200.426 us; speedup vs baseline: 1.3961x; 1.0349x over previous
//
#include <hip/hip_runtime.h>
#include <hip/hip_bf16.h>

// DecorrelatedBatchNorm1d (ZCA whitening), B=65536, F=512, fp32 in/out.
// Pipeline (single path, ws < 6 MB):
//   K1 k_prep3:    xbT = bf16(x)^T (d_out overlay) + colsum
//                  (fp32 LDS-tile transpose; PHASE-B WRITES COALESCED:
//                   256B contiguous per feature per instruction)
//   K2 k_cov:      S = xbT * xbT^T upper-triangle (bf16 MFMA, split-K=32, atomics)
//   K3 k_finalize: mean, E = S/(B-1) corrected - I + eps
//   K4 k_poly s0:  E2 = E@E; G = c3*E + c4*E2        (deg-4 Taylor of (I+E)^-1/2)
//   K5 k_poly s1:  W = I + c1*E + c2*E2 + E2@G -> Wb; tacc = mean^T W
//   K6 k_out_f:    out = (x@W - tacc)*weight + bias  (fp32 x reg-staged -> bf16
//                   swizzled LDS; Wb via global_load_lds; nontemporal out)

#define F 512
#define LDT 65536

typedef unsigned short u16;
using bf16x8 = __attribute__((ext_vector_type(8))) short;
using f32x4  = __attribute__((ext_vector_type(4))) float;

// ---- workspace layout (bytes) ----
#define WS_S      0u
#define WS_COLSUM 1048576u
#define WS_TACC   1050624u
#define WS_MEAN   1052672u
#define WS_E      1054720u
#define WS_E2     (WS_E   + 1048576u)
#define WS_EB     (WS_E2  + 1048576u)
#define WS_E2B    (WS_EB  + 524288u)
#define WS_GB     (WS_E2B + 524288u)
#define WS_WB     (WS_GB  + 524288u)

__device__ __forceinline__ u16 f2bf(float x) {
  union { float f; unsigned u; } v; v.f = x;
  return (u16)((v.u + 0x7fffu + ((v.u >> 16) & 1u)) >> 16);
}

__device__ __forceinline__ void async_cp16(const void* g, void* l) {
  __builtin_amdgcn_global_load_lds(
      (const __attribute__((address_space(1))) unsigned int*)g,
      (__attribute__((address_space(3))) unsigned int*)l, 16, 0, 0);
}

// ---- [128 rows][64 k] bf16 tile staging ----
// LDS dest linear; source pre-swizzled: LDS row r chunk c holds global chunk c^(r&7).
__device__ __forceinline__ void stage_tile(u16* dst, const u16* src, size_t stride, int t) {
#pragma unroll
  for (int q = 0; q < 4; ++q) {
    int idx = q * 256 + t;
    int c = idx >> 3, ko = idx & 7;
    async_cp16(src + (size_t)c * stride + (size_t)((ko ^ (c & 7)) << 3), dst + idx * 8);
  }
}

__device__ __forceinline__ void stage512(u16* dst, const u16* src, size_t stride, int t) {
#pragma unroll
  for (int q = 0; q < 2; ++q) {
    int idx = q * 512 + t;
    int c = idx >> 3, ko = idx & 7;
    async_cp16(src + (size_t)c * stride + (size_t)((ko ^ (c & 7)) << 3), dst + idx * 8);
  }
}

__device__ __forceinline__ void stage64(u16* dst, const u16* src, size_t stride, int t) {
#pragma unroll
  for (int q = 0; q < 2; ++q) {
    int idx = q * 256 + t;
    int r = idx >> 3, ko = idx & 7;
    async_cp16(src + (size_t)r * stride + (size_t)((ko ^ (r & 7)) << 3), dst + idx * 8);
  }
}

// 128x128 tile step, 4 waves (k_cov)
__device__ __forceinline__ void mm_step(const u16* As, const u16* Bs, int wr, int wc,
                                        int l, f32x4 acc[4][4]) {
#pragma unroll
  for (int kh = 0; kh < 2; ++kh) {
    bf16x8 a[4], b[4];
#pragma unroll
    for (int m = 0; m < 4; ++m) {
      int row = wr * 64 + m * 16 + (l & 15);
      int ch = (kh * 4 + (l >> 4)) ^ (row & 7);
      a[m] = *(const bf16x8*)(As + row * 64 + ch * 8);
    }
#pragma unroll
    for (int n = 0; n < 4; ++n) {
      int row = wc * 64 + n * 16 + (l & 15);
      int ch = (kh * 4 + (l >> 4)) ^ (row & 7);
      b[n] = *(const bf16x8*)(Bs + row * 64 + ch * 8);
    }
#pragma unroll
    for (int m = 0; m < 4; ++m)
#pragma unroll
      for (int n = 0; n < 4; ++n)
        acc[m][n] = __builtin_amdgcn_mfma_f32_16x16x32_bf16(a[m], b[n], acc[m][n], 0, 0, 0);
  }
}

// 128x128 tile step, 8 waves (k_out): wave-tile 64x32
__device__ __forceinline__ void mm_step8(const u16* As, const u16* Bs, int wr, int wc,
                                         int l, f32x4 acc[4][2]) {
#pragma unroll
  for (int kh = 0; kh < 2; ++kh) {
    bf16x8 a[4], b[2];
#pragma unroll
    for (int m = 0; m < 4; ++m) {
      int row = wr * 64 + m * 16 + (l & 15);
      int ch = (kh * 4 + (l >> 4)) ^ (row & 7);
      a[m] = *(const bf16x8*)(As + row * 64 + ch * 8);
    }
#pragma unroll
    for (int n = 0; n < 2; ++n) {
      int row = wc * 32 + n * 16 + (l & 15);
      int ch = (kh * 4 + (l >> 4)) ^ (row & 7);
      b[n] = *(const bf16x8*)(Bs + row * 64 + ch * 8);
    }
#pragma unroll
    for (int m = 0; m < 4; ++m)
#pragma unroll
      for (int n = 0; n < 2; ++n)
        acc[m][n] = __builtin_amdgcn_mfma_f32_16x16x32_bf16(a[m], b[n], acc[m][n], 0, 0, 0);
  }
}

// 64x64 tile step, 4 waves (poly)
__device__ __forceinline__ void mm64(const u16* As, const u16* Bs, int wr, int wc,
                                     int l, f32x4 acc[2][2]) {
#pragma unroll
  for (int kh = 0; kh < 2; ++kh) {
    bf16x8 a[2], b[2];
#pragma unroll
    for (int m = 0; m < 2; ++m) {
      int row = wr * 32 + m * 16 + (l & 15);
      int ch = (kh * 4 + (l >> 4)) ^ (row & 7);
      a[m] = *(const bf16x8*)(As + row * 64 + ch * 8);
    }
#pragma unroll
    for (int n = 0; n < 2; ++n) {
      int row = wc * 32 + n * 16 + (l & 15);
      int ch = (kh * 4 + (l >> 4)) ^ (row & 7);
      b[n] = *(const bf16x8*)(Bs + row * 64 + ch * 8);
    }
#pragma unroll
    for (int m = 0; m < 2; ++m)
#pragma unroll
      for (int n = 0; n < 2; ++n)
        acc[m][n] = __builtin_amdgcn_mfma_f32_16x16x32_bf16(a[m], b[n], acc[m][n], 0, 0, 0);
  }
}

// ---------------- K1: transpose + colsum, coalesced xbT writes ----------------
// grid (512, 8), 256 thr; tile = 128 batch rows x 64 feats.
// Phase A: round-1-proven fp32 [128][65] LDS tile + colsum partials.
// Phase B: per store instruction, lanes 0..31 write feature f's 128-k run
// (32 x 8B = 256B contiguous), lanes 32..63 write feature f+1 -> DRAM-burst
// friendly (vs old 64 x 8-16B scattered at 128KB stride).
__global__ __launch_bounds__(256) void k_prep3(const float* __restrict__ x,
                                               u16* __restrict__ xbT,
                                               float* __restrict__ colsum) {
  __shared__ __attribute__((aligned(16))) float tile[128 * 65];
  __shared__ float red[1024];
  const int t = threadIdx.x;
  const int r0 = blockIdx.x * 128, c0 = blockIdx.y * 64;
  const int c4 = t & 15, rg = t >> 4;
  float cs0 = 0, cs1 = 0, cs2 = 0, cs3 = 0;
#pragma unroll
  for (int p = 0; p < 8; ++p) {
    int r = rg + p * 16;
    float4 v = *(const float4*)(x + (size_t)(r0 + r) * F + c0 + c4 * 4);
    cs0 += v.x; cs1 += v.y; cs2 += v.z; cs3 += v.w;
    float* tp = tile + r * 65 + c4 * 4;
    tp[0] = v.x; tp[1] = v.y; tp[2] = v.z; tp[3] = v.w;
  }
  red[rg * 64 + c4 * 4 + 0] = cs0;
  red[rg * 64 + c4 * 4 + 1] = cs1;
  red[rg * 64 + c4 * 4 + 2] = cs2;
  red[rg * 64 + c4 * 4 + 3] = cs3;
  __syncthreads();
  const int l = t & 63, w = t >> 6;
  const int half = l >> 5, kb = (l & 31) * 4;
#pragma unroll
  for (int it = 0; it < 8; ++it) {
    int f = w * 16 + it * 2 + half;
    ushort4 o;
    o.x = f2bf(tile[(kb + 0) * 65 + f]);
    o.y = f2bf(tile[(kb + 1) * 65 + f]);
    o.z = f2bf(tile[(kb + 2) * 65 + f]);
    o.w = f2bf(tile[(kb + 3) * 65 + f]);
    *(ushort4*)(xbT + (size_t)(c0 + f) * LDT + r0 + kb) = o;
  }
  if (t < 64) {
    float s = 0;
#pragma unroll
    for (int g = 0; g < 16; ++g) s += red[g * 64 + t];
    atomicAdd(colsum + c0 + t, s);
  }
}

// ---------------- K2: S = X^T X, upper-triangle 128-tiles, split-K=32 ----------------
__global__ __launch_bounds__(256) void k_cov(const u16* __restrict__ xbT,
                                             float* __restrict__ S) {
  __shared__ __attribute__((aligned(16))) u16 As[2][128 * 64];
  __shared__ __attribute__((aligned(16))) u16 Bs[2][128 * 64];
  const int b = blockIdx.x;
  const int i = b >> 3;               // 0..39
  const int slab = (b & 7) * 4 + i / 10;
  const int tid = i % 10;
  int ta, tb;
  if (tid < 4)      { ta = 0; tb = tid; }
  else if (tid < 7) { ta = 1; tb = tid - 3; }
  else if (tid < 9) { ta = 2; tb = tid - 5; }
  else              { ta = 3; tb = 3; }
  const int a0 = ta * 128, b0 = tb * 128;
  const size_t kbase = (size_t)slab * 2048;
  const int t = threadIdx.x;
  const int l = t & 63, w = t >> 6, wr = w >> 1, wc = w & 1;
  f32x4 acc[4][4] = {};
  const u16* Abase = xbT + (size_t)a0 * LDT + kbase;
  const u16* Bbase = xbT + (size_t)b0 * LDT + kbase;
  stage_tile(As[0], Abase, LDT, t);
  stage_tile(Bs[0], Bbase, LDT, t);
  __syncthreads();
  for (int it = 0; it < 32; ++it) {
    int cur = it & 1;
    if (it < 31) {
      stage_tile(As[cur ^ 1], Abase + (it + 1) * 64, LDT, t);
      stage_tile(Bs[cur ^ 1], Bbase + (it + 1) * 64, LDT, t);
    }
    mm_step(As[cur], Bs[cur], wr, wc, l, acc);
    __syncthreads();
  }
#pragma unroll
  for (int m = 0; m < 4; ++m) {
    int rg = a0 + wr * 64 + m * 16 + ((l >> 4) << 2);
#pragma unroll
    for (int n = 0; n < 4; ++n) {
      int cg = b0 + wc * 64 + n * 16 + (l & 15);
#pragma unroll
      for (int r = 0; r < 4; ++r)
        atomicAdd(S + (size_t)(rg + r) * F + cg, acc[m][n][r]);
    }
  }
}

// ---------------- K3: finalize mean + E = cov - I ----------------
__global__ __launch_bounds__(256) void k_finalize(const float* __restrict__ S,
                                                  const float* __restrict__ colsum,
                                                  float* __restrict__ mean,
                                                  float* __restrict__ E,
                                                  u16* __restrict__ Eb) {
  int gid = blockIdx.x * 256 + threadIdx.x;
  int i = gid >> 9, j = gid & 511;
  float mi = colsum[i] * (1.0f / 65536.0f);
  float mj = colsum[j] * (1.0f / 65536.0f);
  float sv = ((i >> 7) <= (j >> 7)) ? S[(size_t)i * F + j] : S[(size_t)j * F + i];
  float cov = (sv - 65536.0f * mi * mj) * (1.0f / 65535.0f);
  float e = cov + ((i == j) ? (0.001f - 1.0f) : 0.0f);
  E[gid] = e;
  Eb[gid] = f2bf(e);
  if (gid < F) mean[gid] = colsum[gid] * (1.0f / 65536.0f);
}

// ---------------- K4/K5: degree-4 Taylor of (I+E)^(-1/2) ----------------
__global__ __launch_bounds__(256) void k_poly(char* __restrict__ wsb, int stg) {
  __shared__ __attribute__((aligned(16))) u16 As[2][64 * 64];
  __shared__ __attribute__((aligned(16))) u16 Bs[2][64 * 64];
  const int tile = blockIdx.x;
  const int tr = tile >> 3, tc = tile & 7;
  const int r0 = tr * 64, c0 = tc * 64;
  const u16* Eb  = (const u16*)(wsb + WS_EB);
  const u16* E2b = (const u16*)(wsb + WS_E2B);
  const u16* Gb  = (const u16*)(wsb + WS_GB);
  const u16* Ab; const u16* Bb;
  if (stg == 0) { Ab = Eb;  Bb = Eb; }
  else          { Ab = E2b; Bb = Gb; }
  const int t = threadIdx.x;
  const int l = t & 63, w = t >> 6, wr = w >> 1, wc = w & 1;
  f32x4 acc[2][2] = {};
  stage64(As[0], Ab + (size_t)r0 * F, F, t);
  stage64(Bs[0], Bb + (size_t)c0 * F, F, t);
  __syncthreads();
  for (int it = 0; it < 8; ++it) {
    int cur = it & 1;
    if (it < 7) {
      stage64(As[cur ^ 1], Ab + (size_t)r0 * F + (it + 1) * 64, F, t);
      stage64(Bs[cur ^ 1], Bb + (size_t)c0 * F + (it + 1) * 64, F, t);
    }
    mm64(As[cur], Bs[cur], wr, wc, l, acc);
    __syncthreads();
  }
  const float* Ef  = (const float*)(wsb + WS_E);
  const float* E2f = (const float*)(wsb + WS_E2);
  const float* mean = (const float*)(wsb + WS_MEAN);
  float* tacc = (float*)(wsb + WS_TACC);
  const float c1 = -0.5f, c2 = 0.375f, c3 = -0.3125f, c4 = 35.0f / 128.0f;
#pragma unroll
  for (int n = 0; n < 2; ++n) {
    int cg = c0 + wc * 32 + n * 16 + (l & 15);
    float ts = 0.0f;
#pragma unroll
    for (int m = 0; m < 2; ++m) {
#pragma unroll
      for (int r = 0; r < 4; ++r) {
        int rg = r0 + wr * 32 + m * 16 + ((l >> 4) << 2) + r;
        size_t o = (size_t)rg * F + cg;
        float v = acc[m][n][r];
        if (stg == 0) {
          ((float*)(wsb + WS_E2))[o] = v;
          ((u16*)(wsb + WS_E2B))[o] = f2bf(v);
          ((u16*)(wsb + WS_GB))[o]  = f2bf(c3 * Ef[o] + c4 * v);
        } else {
          float wv = c1 * Ef[o] + c2 * E2f[o] + v + ((rg == cg) ? 1.0f : 0.0f);
          ((u16*)(wsb + WS_WB))[o] = f2bf(wv);
          ts += mean[rg] * wv;
        }
      }
    }
    if (stg == 1) atomicAdd(tacc + cg, ts);
  }
}

// ---------------- K6: out = (x@W - tacc)*w + b ----------------
// 128x128 tiles, 8 waves, XCD-pinned. A: fp32 x reg-staged -> bf16 swizzled LDS
// (x is L3-resident by now). B: Wb via global_load_lds. Nontemporal out.
__global__ __launch_bounds__(512) void k_out_f(const float* __restrict__ x,
                                               const u16* __restrict__ Wb,
                                               const float* __restrict__ tacc,
                                               const float* __restrict__ wgt,
                                               const float* __restrict__ bias,
                                               float* __restrict__ out) {
  __shared__ __attribute__((aligned(16))) u16 As[2][128 * 64];
  __shared__ __attribute__((aligned(16))) u16 Bs[2][128 * 64];
  const int b = blockIdx.x;
  const int i = b >> 3;
  const int rt = (b & 7) * 64 + (i >> 2), ct = i & 3;
  const int i0 = rt * 128, j0 = ct * 128;
  const int t = threadIdx.x;
  const int l = t & 63, w = t >> 6, wr = w >> 2, wc = w & 3;
  f32x4 acc[4][2] = {};
  float4 ld[4];
  stage512(Bs[0], Wb + (size_t)j0 * F, F, t);
#pragma unroll
  for (int q = 0; q < 4; ++q) {
    int idx = q * 512 + t, r = idx >> 4, kc = idx & 15;
    ld[q] = *(const float4*)(x + (size_t)(i0 + r) * F + kc * 4);
  }
#pragma unroll
  for (int q = 0; q < 4; ++q) {
    int idx = q * 512 + t, r = idx >> 4, kc = idx & 15;
    ushort4 o;
    o.x = f2bf(ld[q].x); o.y = f2bf(ld[q].y); o.z = f2bf(ld[q].z); o.w = f2bf(ld[q].w);
    *(ushort4*)(As[0] + r * 64 + (((kc >> 1) ^ (r & 7)) << 3) + ((kc & 1) << 2)) = o;
  }
  __syncthreads();
  for (int it = 0; it < 8; ++it) {
    int cur = it & 1;
    if (it < 7) {
      int kk = (it + 1) * 64;
#pragma unroll
      for (int q = 0; q < 4; ++q) {
        int idx = q * 512 + t, r = idx >> 4, kc = idx & 15;
        ld[q] = *(const float4*)(x + (size_t)(i0 + r) * F + kk + kc * 4);
      }
      stage512(Bs[cur ^ 1], Wb + (size_t)j0 * F + kk, F, t);
    }
    mm_step8(As[cur], Bs[cur], wr, wc, l, acc);
    if (it < 7) {
#pragma unroll
      for (int q = 0; q < 4; ++q) {
        int idx = q * 512 + t, r = idx >> 4, kc = idx & 15;
        ushort4 o;
        o.x = f2bf(ld[q].x); o.y = f2bf(ld[q].y); o.z = f2bf(ld[q].z); o.w = f2bf(ld[q].w);
        *(ushort4*)(As[cur ^ 1] + r * 64 + (((kc >> 1) ^ (r & 7)) << 3) + ((kc & 1) << 2)) = o;
      }
    }
    __syncthreads();
  }
#pragma unroll
  for (int n = 0; n < 2; ++n) {
    int cg = j0 + wc * 32 + n * 16 + (l & 15);
    float mv = tacc[cg];
    float wv = wgt[cg], bv = bias[cg];
#pragma unroll
    for (int m = 0; m < 4; ++m) {
      int rb = i0 + wr * 64 + m * 16 + ((l >> 4) << 2);
#pragma unroll
      for (int r = 0; r < 4; ++r) {
        size_t o = (size_t)(rb + r) * F + cg;
        __builtin_nontemporal_store((acc[m][n][r] - mv) * wv + bv, out + o);
      }
    }
  }
}

extern "C" void kernel_launch(void* const* d_in, const int* in_sizes, int n_in,
                              void* d_out, int out_size, void* d_ws, size_t ws_size,
                              hipStream_t stream) {
  (void)in_sizes; (void)n_in; (void)out_size; (void)ws_size;
  const float* x      = (const float*)d_in[0];
  const float* weight = (const float*)d_in[1];
  const float* bias   = (const float*)d_in[2];
  float* out = (float*)d_out;
  char* ws   = (char*)d_ws;
  // xbT (64 MiB) overlays d_out; only read by k_cov, dead before k_out_f writes.
  u16* xbT = (u16*)d_out;

  float* S      = (float*)(ws + WS_S);
  float* colsum = (float*)(ws + WS_COLSUM);
  float* tacc   = (float*)(ws + WS_TACC);
  float* mean   = (float*)(ws + WS_MEAN);

  hipMemsetAsync(ws, 0, WS_MEAN, stream);  // zero S + colsum + tacc

  k_prep3<<<dim3(512, 8), dim3(256), 0, stream>>>(x, xbT, colsum);
  k_cov<<<dim3(320), dim3(256), 0, stream>>>(xbT, S);
  k_finalize<<<dim3(1024), dim3(256), 0, stream>>>(S, colsum, mean,
                                                   (float*)(ws + WS_E),
                                                   (u16*)(ws + WS_EB));
  k_poly<<<dim3(64), dim3(256), 0, stream>>>(ws, 0);
  k_poly<<<dim3(64), dim3(256), 0, stream>>>(ws, 1);
  k_out_f<<<dim3(2048), dim3(512), 0, stream>>>(x, (u16*)(ws + WS_WB),
                                                tacc, weight, bias, out);
}

// Round 9
// 199.963 us; speedup vs baseline: 1.3994x; 1.0023x over previous
//
#include <hip/hip_runtime.h>
#include <hip/hip_bf16.h>

// DecorrelatedBatchNorm1d (ZCA whitening), B=65536, F=512, fp32 in/out.
// Pipeline (single path, ws < 6 MB):
//   K0 k_zero:     zero S + colsum + tacc (custom fill; rocclr fill was 77 us!)
//   K1 k_prep3:    xbT = bf16(x)^T (d_out overlay) + colsum
//                  (fp32 LDS-tile transpose; coalesced 256B-per-feature writes)
//   K2 k_cov:      S = xbT * xbT^T upper-triangle (bf16 MFMA, split-K, atomics)
//   K3 k_finalize: mean, E = S/(B-1) corrected - I + eps
//   K4 k_poly s0:  E2 = E@E; G = c3*E + c4*E2        (deg-4 Taylor of (I+E)^-1/2)
//   K5 k_poly s1:  W = I + c1*E + c2*E2 + E2@G -> Wb; tacc = mean^T W
//   K6 k_out_f:    out = (x@W - tacc)*weight + bias  (fp32 x reg-staged -> bf16
//                   swizzled LDS; Wb via global_load_lds; nontemporal out)

#define F 512
#define LDT 65536

typedef unsigned short u16;
using bf16x8 = __attribute__((ext_vector_type(8))) short;
using f32x4  = __attribute__((ext_vector_type(4))) float;

// ---- workspace layout (bytes) ----
#define WS_S      0u
#define WS_COLSUM 1048576u
#define WS_TACC   1050624u
#define WS_MEAN   1052672u
#define WS_E      1054720u
#define WS_E2     (WS_E   + 1048576u)
#define WS_EB     (WS_E2  + 1048576u)
#define WS_E2B    (WS_EB  + 524288u)
#define WS_GB     (WS_E2B + 524288u)
#define WS_WB     (WS_GB  + 524288u)

__device__ __forceinline__ u16 f2bf(float x) {
  union { float f; unsigned u; } v; v.f = x;
  return (u16)((v.u + 0x7fffu + ((v.u >> 16) & 1u)) >> 16);
}

__device__ __forceinline__ void async_cp16(const void* g, void* l) {
  __builtin_amdgcn_global_load_lds(
      (const __attribute__((address_space(1))) unsigned int*)g,
      (__attribute__((address_space(3))) unsigned int*)l, 16, 0, 0);
}

// ---- [128 rows][64 k] bf16 tile staging ----
// LDS dest linear; source pre-swizzled: LDS row r chunk c holds global chunk c^(r&7).
__device__ __forceinline__ void stage_tile(u16* dst, const u16* src, size_t stride, int t) {
#pragma unroll
  for (int q = 0; q < 4; ++q) {
    int idx = q * 256 + t;
    int c = idx >> 3, ko = idx & 7;
    async_cp16(src + (size_t)c * stride + (size_t)((ko ^ (c & 7)) << 3), dst + idx * 8);
  }
}

__device__ __forceinline__ void stage512(u16* dst, const u16* src, size_t stride, int t) {
#pragma unroll
  for (int q = 0; q < 2; ++q) {
    int idx = q * 512 + t;
    int c = idx >> 3, ko = idx & 7;
    async_cp16(src + (size_t)c * stride + (size_t)((ko ^ (c & 7)) << 3), dst + idx * 8);
  }
}

__device__ __forceinline__ void stage64(u16* dst, const u16* src, size_t stride, int t) {
#pragma unroll
  for (int q = 0; q < 2; ++q) {
    int idx = q * 256 + t;
    int r = idx >> 3, ko = idx & 7;
    async_cp16(src + (size_t)r * stride + (size_t)((ko ^ (r & 7)) << 3), dst + idx * 8);
  }
}

// 128x128 tile step, 4 waves (k_cov)
__device__ __forceinline__ void mm_step(const u16* As, const u16* Bs, int wr, int wc,
                                        int l, f32x4 acc[4][4]) {
#pragma unroll
  for (int kh = 0; kh < 2; ++kh) {
    bf16x8 a[4], b[4];
#pragma unroll
    for (int m = 0; m < 4; ++m) {
      int row = wr * 64 + m * 16 + (l & 15);
      int ch = (kh * 4 + (l >> 4)) ^ (row & 7);
      a[m] = *(const bf16x8*)(As + row * 64 + ch * 8);
    }
#pragma unroll
    for (int n = 0; n < 4; ++n) {
      int row = wc * 64 + n * 16 + (l & 15);
      int ch = (kh * 4 + (l >> 4)) ^ (row & 7);
      b[n] = *(const bf16x8*)(Bs + row * 64 + ch * 8);
    }
#pragma unroll
    for (int m = 0; m < 4; ++m)
#pragma unroll
      for (int n = 0; n < 4; ++n)
        acc[m][n] = __builtin_amdgcn_mfma_f32_16x16x32_bf16(a[m], b[n], acc[m][n], 0, 0, 0);
  }
}

// 128x128 tile step, 8 waves (k_out): wave-tile 64x32
__device__ __forceinline__ void mm_step8(const u16* As, const u16* Bs, int wr, int wc,
                                         int l, f32x4 acc[4][2]) {
#pragma unroll
  for (int kh = 0; kh < 2; ++kh) {
    bf16x8 a[4], b[2];
#pragma unroll
    for (int m = 0; m < 4; ++m) {
      int row = wr * 64 + m * 16 + (l & 15);
      int ch = (kh * 4 + (l >> 4)) ^ (row & 7);
      a[m] = *(const bf16x8*)(As + row * 64 + ch * 8);
    }
#pragma unroll
    for (int n = 0; n < 2; ++n) {
      int row = wc * 32 + n * 16 + (l & 15);
      int ch = (kh * 4 + (l >> 4)) ^ (row & 7);
      b[n] = *(const bf16x8*)(Bs + row * 64 + ch * 8);
    }
#pragma unroll
    for (int m = 0; m < 4; ++m)
#pragma unroll
      for (int n = 0; n < 2; ++n)
        acc[m][n] = __builtin_amdgcn_mfma_f32_16x16x32_bf16(a[m], b[n], acc[m][n], 0, 0, 0);
  }
}

// 64x64 tile step, 4 waves (poly)
__device__ __forceinline__ void mm64(const u16* As, const u16* Bs, int wr, int wc,
                                     int l, f32x4 acc[2][2]) {
#pragma unroll
  for (int kh = 0; kh < 2; ++kh) {
    bf16x8 a[2], b[2];
#pragma unroll
    for (int m = 0; m < 2; ++m) {
      int row = wr * 32 + m * 16 + (l & 15);
      int ch = (kh * 4 + (l >> 4)) ^ (row & 7);
      a[m] = *(const bf16x8*)(As + row * 64 + ch * 8);
    }
#pragma unroll
    for (int n = 0; n < 2; ++n) {
      int row = wc * 32 + n * 16 + (l & 15);
      int ch = (kh * 4 + (l >> 4)) ^ (row & 7);
      b[n] = *(const bf16x8*)(Bs + row * 64 + ch * 8);
    }
#pragma unroll
    for (int m = 0; m < 2; ++m)
#pragma unroll
      for (int n = 0; n < 2; ++n)
        acc[m][n] = __builtin_amdgcn_mfma_f32_16x16x32_bf16(a[m], b[n], acc[m][n], 0, 0, 0);
  }
}

// ---------------- K0: zero S + colsum + tacc (1,052,672 B = 65792 uint4) --------
__global__ __launch_bounds__(256) void k_zero(uint4* __restrict__ p) {
  p[(size_t)blockIdx.x * 256 + threadIdx.x] = uint4{0u, 0u, 0u, 0u};
}

// ---------------- K1: transpose + colsum, coalesced xbT writes ----------------
// grid (512, 8), 256 thr; tile = 128 batch rows x 64 feats.
// Phase A: fp32 [128][65] LDS tile + colsum partials.
// Phase B: per store instruction, lanes 0..31 write feature f's 128-k run
// (32 x 8B = 256B contiguous), lanes 32..63 write feature f+1.
__global__ __launch_bounds__(256) void k_prep3(const float* __restrict__ x,
                                               u16* __restrict__ xbT,
                                               float* __restrict__ colsum) {
  __shared__ __attribute__((aligned(16))) float tile[128 * 65];
  __shared__ float red[1024];
  const int t = threadIdx.x;
  const int r0 = blockIdx.x * 128, c0 = blockIdx.y * 64;
  const int c4 = t & 15, rg = t >> 4;
  float cs0 = 0, cs1 = 0, cs2 = 0, cs3 = 0;
#pragma unroll
  for (int p = 0; p < 8; ++p) {
    int r = rg + p * 16;
    float4 v = *(const float4*)(x + (size_t)(r0 + r) * F + c0 + c4 * 4);
    cs0 += v.x; cs1 += v.y; cs2 += v.z; cs3 += v.w;
    float* tp = tile + r * 65 + c4 * 4;
    tp[0] = v.x; tp[1] = v.y; tp[2] = v.z; tp[3] = v.w;
  }
  red[rg * 64 + c4 * 4 + 0] = cs0;
  red[rg * 64 + c4 * 4 + 1] = cs1;
  red[rg * 64 + c4 * 4 + 2] = cs2;
  red[rg * 64 + c4 * 4 + 3] = cs3;
  __syncthreads();
  const int l = t & 63, w = t >> 6;
  const int half = l >> 5, kb = (l & 31) * 4;
#pragma unroll
  for (int it = 0; it < 8; ++it) {
    int f = w * 16 + it * 2 + half;
    ushort4 o;
    o.x = f2bf(tile[(kb + 0) * 65 + f]);
    o.y = f2bf(tile[(kb + 1) * 65 + f]);
    o.z = f2bf(tile[(kb + 2) * 65 + f]);
    o.w = f2bf(tile[(kb + 3) * 65 + f]);
    *(ushort4*)(xbT + (size_t)(c0 + f) * LDT + r0 + kb) = o;
  }
  if (t < 64) {
    float s = 0;
#pragma unroll
    for (int g = 0; g < 16; ++g) s += red[g * 64 + t];
    atomicAdd(colsum + c0 + t, s);
  }
}

// ---------------- K2: S = X^T X, upper-triangle 128-tiles, split-K ----------------
__global__ __launch_bounds__(256) void k_cov(const u16* __restrict__ xbT,
                                             float* __restrict__ S) {
  __shared__ __attribute__((aligned(16))) u16 As[2][128 * 64];
  __shared__ __attribute__((aligned(16))) u16 Bs[2][128 * 64];
  const int b = blockIdx.x;
  const int i = b >> 3;               // 0..39
  const int slab = (b & 7) * 4 + i / 10;
  const int tid = i % 10;
  int ta, tb;
  if (tid < 4)      { ta = 0; tb = tid; }
  else if (tid < 7) { ta = 1; tb = tid - 3; }
  else if (tid < 9) { ta = 2; tb = tid - 5; }
  else              { ta = 3; tb = 3; }
  const int a0 = ta * 128, b0 = tb * 128;
  const size_t kbase = (size_t)slab * 2048;
  const int t = threadIdx.x;
  const int l = t & 63, w = t >> 6, wr = w >> 1, wc = w & 1;
  f32x4 acc[4][4] = {};
  const u16* Abase = xbT + (size_t)a0 * LDT + kbase;
  const u16* Bbase = xbT + (size_t)b0 * LDT + kbase;
  stage_tile(As[0], Abase, LDT, t);
  stage_tile(Bs[0], Bbase, LDT, t);
  __syncthreads();
  for (int it = 0; it < 32; ++it) {
    int cur = it & 1;
    if (it < 31) {
      stage_tile(As[cur ^ 1], Abase + (it + 1) * 64, LDT, t);
      stage_tile(Bs[cur ^ 1], Bbase + (it + 1) * 64, LDT, t);
    }
    mm_step(As[cur], Bs[cur], wr, wc, l, acc);
    __syncthreads();
  }
#pragma unroll
  for (int m = 0; m < 4; ++m) {
    int rg = a0 + wr * 64 + m * 16 + ((l >> 4) << 2);
#pragma unroll
    for (int n = 0; n < 4; ++n) {
      int cg = b0 + wc * 64 + n * 16 + (l & 15);
#pragma unroll
      for (int r = 0; r < 4; ++r)
        atomicAdd(S + (size_t)(rg + r) * F + cg, acc[m][n][r]);
    }
  }
}

// ---------------- K3: finalize mean + E = cov - I ----------------
__global__ __launch_bounds__(256) void k_finalize(const float* __restrict__ S,
                                                  const float* __restrict__ colsum,
                                                  float* __restrict__ mean,
                                                  float* __restrict__ E,
                                                  u16* __restrict__ Eb) {
  int gid = blockIdx.x * 256 + threadIdx.x;
  int i = gid >> 9, j = gid & 511;
  float mi = colsum[i] * (1.0f / 65536.0f);
  float mj = colsum[j] * (1.0f / 65536.0f);
  float sv = ((i >> 7) <= (j >> 7)) ? S[(size_t)i * F + j] : S[(size_t)j * F + i];
  float cov = (sv - 65536.0f * mi * mj) * (1.0f / 65535.0f);
  float e = cov + ((i == j) ? (0.001f - 1.0f) : 0.0f);
  E[gid] = e;
  Eb[gid] = f2bf(e);
  if (gid < F) mean[gid] = colsum[gid] * (1.0f / 65536.0f);
}

// ---------------- K4/K5: degree-4 Taylor of (I+E)^(-1/2) ----------------
__global__ __launch_bounds__(256) void k_poly(char* __restrict__ wsb, int stg) {
  __shared__ __attribute__((aligned(16))) u16 As[2][64 * 64];
  __shared__ __attribute__((aligned(16))) u16 Bs[2][64 * 64];
  const int tile = blockIdx.x;
  const int tr = tile >> 3, tc = tile & 7;
  const int r0 = tr * 64, c0 = tc * 64;
  const u16* Eb  = (const u16*)(wsb + WS_EB);
  const u16* E2b = (const u16*)(wsb + WS_E2B);
  const u16* Gb  = (const u16*)(wsb + WS_GB);
  const u16* Ab; const u16* Bb;
  if (stg == 0) { Ab = Eb;  Bb = Eb; }
  else          { Ab = E2b; Bb = Gb; }
  const int t = threadIdx.x;
  const int l = t & 63, w = t >> 6, wr = w >> 1, wc = w & 1;
  f32x4 acc[2][2] = {};
  stage64(As[0], Ab + (size_t)r0 * F, F, t);
  stage64(Bs[0], Bb + (size_t)c0 * F, F, t);
  __syncthreads();
  for (int it = 0; it < 8; ++it) {
    int cur = it & 1;
    if (it < 7) {
      stage64(As[cur ^ 1], Ab + (size_t)r0 * F + (it + 1) * 64, F, t);
      stage64(Bs[cur ^ 1], Bb + (size_t)c0 * F + (it + 1) * 64, F, t);
    }
    mm64(As[cur], Bs[cur], wr, wc, l, acc);
    __syncthreads();
  }
  const float* Ef  = (const float*)(wsb + WS_E);
  const float* E2f = (const float*)(wsb + WS_E2);
  const float* mean = (const float*)(wsb + WS_MEAN);
  float* tacc = (float*)(wsb + WS_TACC);
  const float c1 = -0.5f, c2 = 0.375f, c3 = -0.3125f, c4 = 35.0f / 128.0f;
#pragma unroll
  for (int n = 0; n < 2; ++n) {
    int cg = c0 + wc * 32 + n * 16 + (l & 15);
    float ts = 0.0f;
#pragma unroll
    for (int m = 0; m < 2; ++m) {
#pragma unroll
      for (int r = 0; r < 4; ++r) {
        int rg = r0 + wr * 32 + m * 16 + ((l >> 4) << 2) + r;
        size_t o = (size_t)rg * F + cg;
        float v = acc[m][n][r];
        if (stg == 0) {
          ((float*)(wsb + WS_E2))[o] = v;
          ((u16*)(wsb + WS_E2B))[o] = f2bf(v);
          ((u16*)(wsb + WS_GB))[o]  = f2bf(c3 * Ef[o] + c4 * v);
        } else {
          float wv = c1 * Ef[o] + c2 * E2f[o] + v + ((rg == cg) ? 1.0f : 0.0f);
          ((u16*)(wsb + WS_WB))[o] = f2bf(wv);
          ts += mean[rg] * wv;
        }
      }
    }
    if (stg == 1) atomicAdd(tacc + cg, ts);
  }
}

// ---------------- K6: out = (x@W - tacc)*w + b ----------------
// 128x128 tiles, 8 waves, XCD-pinned. A: fp32 x reg-staged -> bf16 swizzled LDS
// (x is L3-resident by now). B: Wb via global_load_lds. Nontemporal out.
__global__ __launch_bounds__(512) void k_out_f(const float* __restrict__ x,
                                               const u16* __restrict__ Wb,
                                               const float* __restrict__ tacc,
                                               const float* __restrict__ wgt,
                                               const float* __restrict__ bias,
                                               float* __restrict__ out) {
  __shared__ __attribute__((aligned(16))) u16 As[2][128 * 64];
  __shared__ __attribute__((aligned(16))) u16 Bs[2][128 * 64];
  const int b = blockIdx.x;
  const int i = b >> 3;
  const int rt = (b & 7) * 64 + (i >> 2), ct = i & 3;
  const int i0 = rt * 128, j0 = ct * 128;
  const int t = threadIdx.x;
  const int l = t & 63, w = t >> 6, wr = w >> 2, wc = w & 3;
  f32x4 acc[4][2] = {};
  float4 ld[4];
  stage512(Bs[0], Wb + (size_t)j0 * F, F, t);
#pragma unroll
  for (int q = 0; q < 4; ++q) {
    int idx = q * 512 + t, r = idx >> 4, kc = idx & 15;
    ld[q] = *(const float4*)(x + (size_t)(i0 + r) * F + kc * 4);
  }
#pragma unroll
  for (int q = 0; q < 4; ++q) {
    int idx = q * 512 + t, r = idx >> 4, kc = idx & 15;
    ushort4 o;
    o.x = f2bf(ld[q].x); o.y = f2bf(ld[q].y); o.z = f2bf(ld[q].z); o.w = f2bf(ld[q].w);
    *(ushort4*)(As[0] + r * 64 + (((kc >> 1) ^ (r & 7)) << 3) + ((kc & 1) << 2)) = o;
  }
  __syncthreads();
  for (int it = 0; it < 8; ++it) {
    int cur = it & 1;
    if (it < 7) {
      int kk = (it + 1) * 64;
#pragma unroll
      for (int q = 0; q < 4; ++q) {
        int idx = q * 512 + t, r = idx >> 4, kc = idx & 15;
        ld[q] = *(const float4*)(x + (size_t)(i0 + r) * F + kk + kc * 4);
      }
      stage512(Bs[cur ^ 1], Wb + (size_t)j0 * F + kk, F, t);
    }
    mm_step8(As[cur], Bs[cur], wr, wc, l, acc);
    if (it < 7) {
#pragma unroll
      for (int q = 0; q < 4; ++q) {
        int idx = q * 512 + t, r = idx >> 4, kc = idx & 15;
        ushort4 o;
        o.x = f2bf(ld[q].x); o.y = f2bf(ld[q].y); o.z = f2bf(ld[q].z); o.w = f2bf(ld[q].w);
        *(ushort4*)(As[cur ^ 1] + r * 64 + (((kc >> 1) ^ (r & 7)) << 3) + ((kc & 1) << 2)) = o;
      }
    }
    __syncthreads();
  }
#pragma unroll
  for (int n = 0; n < 2; ++n) {
    int cg = j0 + wc * 32 + n * 16 + (l & 15);
    float mv = tacc[cg];
    float wv = wgt[cg], bv = bias[cg];
#pragma unroll
    for (int m = 0; m < 4; ++m) {
      int rb = i0 + wr * 64 + m * 16 + ((l >> 4) << 2);
#pragma unroll
      for (int r = 0; r < 4; ++r) {
        size_t o = (size_t)(rb + r) * F + cg;
        __builtin_nontemporal_store((acc[m][n][r] - mv) * wv + bv, out + o);
      }
    }
  }
}

extern "C" void kernel_launch(void* const* d_in, const int* in_sizes, int n_in,
                              void* d_out, int out_size, void* d_ws, size_t ws_size,
                              hipStream_t stream) {
  (void)in_sizes; (void)n_in; (void)out_size; (void)ws_size;
  const float* x      = (const float*)d_in[0];
  const float* weight = (const float*)d_in[1];
  const float* bias   = (const float*)d_in[2];
  float* out = (float*)d_out;
  char* ws   = (char*)d_ws;
  // xbT (64 MiB) overlays d_out; only read by k_cov, dead before k_out_f writes.
  u16* xbT = (u16*)d_out;

  float* S      = (float*)(ws + WS_S);
  float* colsum = (float*)(ws + WS_COLSUM);
  float* tacc   = (float*)(ws + WS_TACC);
  float* mean   = (float*)(ws + WS_MEAN);

  // zero S + colsum + tacc: 1,052,672 B = 65792 uint4 = 257 blocks x 256 thr
  k_zero<<<dim3(257), dim3(256), 0, stream>>>((uint4*)ws);

  k_prep3<<<dim3(512, 8), dim3(256), 0, stream>>>(x, xbT, colsum);
  k_cov<<<dim3(320), dim3(256), 0, stream>>>(xbT, S);
  k_finalize<<<dim3(1024), dim3(256), 0, stream>>>(S, colsum, mean,
                                                   (float*)(ws + WS_E),
                                                   (u16*)(ws + WS_EB));
  k_poly<<<dim3(64), dim3(256), 0, stream>>>(ws, 0);
  k_poly<<<dim3(64), dim3(256), 0, stream>>>(ws, 1);
  k_out_f<<<dim3(2048), dim3(512), 0, stream>>>(x, (u16*)(ws + WS_WB),
                                                tacc, weight, bias, out);
}